// Round 1
// baseline (258.206 us; speedup 1.0000x reference)
//
#include <hip/hip_runtime.h>
#include <hip/hip_bf16.h>

typedef unsigned short u16;
typedef __attribute__((ext_vector_type(8))) short short8;
typedef __attribute__((ext_vector_type(4))) float f32x4;
typedef __attribute__((ext_vector_type(16))) float f32x16;

__device__ inline u16 f2bf(float f) {
  unsigned u = __float_as_uint(f);
  u += 0x7fffu + ((u >> 16) & 1u);   // round-to-nearest-even
  return (u16)(u >> 16);
}

// ---------------- cast fp32 -> bf16 (vectorized x4) ----------------
__global__ __launch_bounds__(256) void cast_kernel(const float* __restrict__ in,
                                                   u16* __restrict__ out, int n4) {
  int i = blockIdx.x * 256 + threadIdx.x;
  if (i >= n4) return;
  float4 v = ((const float4*)in)[i];
  ushort4 o;
  o.x = f2bf(v.x); o.y = f2bf(v.y); o.z = f2bf(v.z); o.w = f2bf(v.w);
  ((ushort4*)out)[i] = o;
}

// ---------------- transpose-cast: fp32 [K][N] -> bf16 [N][K] ----------------
__global__ __launch_bounds__(256) void tcast_kernel(const float* __restrict__ in,
                                                    u16* __restrict__ out, int K, int N) {
  __shared__ float tile[32][33];
  int bx = blockIdx.x * 32;  // N offset
  int by = blockIdx.y * 32;  // K offset
  int tx = threadIdx.x & 31, ty = threadIdx.x >> 5;
#pragma unroll
  for (int i = 0; i < 4; i++) {
    int r = ty + i * 8;
    tile[r][tx] = in[(size_t)(by + r) * N + bx + tx];
  }
  __syncthreads();
#pragma unroll
  for (int i = 0; i < 4; i++) {
    int r = ty + i * 8;
    out[(size_t)(bx + r) * K + by + tx] = f2bf(tile[tx][r]);
  }
}

// ---------------- pack K,V into fragment-major layout ----------------
__global__ __launch_bounds__(256) void pack_kv(const u16* __restrict__ kbuf,
                                               const u16* __restrict__ vbuf,
                                               u16* __restrict__ kpack,
                                               u16* __restrict__ vpack) {
  __shared__ __align__(16) u16 ktile[64 * 72];
  __shared__ __align__(16) u16 vtile[64 * 72];
  int t = threadIdx.x;
  int kt = blockIdx.x, h = blockIdx.y, b = blockIdx.z;
  int bh = b * 16 + h;
  size_t rb = (size_t)(b * 2048 + kt * 64);
#pragma unroll
  for (int i = 0; i < 2; i++) {
    int idx = i * 256 + t; int r = idx >> 3, c8 = (idx & 7) * 8;
    *(uint4*)&ktile[r * 72 + c8] = *(const uint4*)(kbuf + (rb + r) * 1024 + h * 64 + c8);
    *(uint4*)&vtile[r * 72 + c8] = *(const uint4*)(vbuf + (rb + r) * 1024 + h * 64 + c8);
  }
  __syncthreads();
  u16* kd = kpack + ((size_t)bh * 32 + kt) * 4096;
  u16* vd = vpack + ((size_t)bh * 32 + kt) * 4096;
#pragma unroll
  for (int i = 0; i < 2; i++) {
    int idx = i * 256 + t;
    int j = idx >> 6, lane = idx & 63, l31 = lane & 31, hi5 = lane >> 5;
    *(uint4*)(kd + j * 512 + lane * 8) =
        *(const uint4*)&ktile[((j >> 2) * 32 + l31) * 72 + (j & 3) * 16 + hi5 * 8];
    union { u16 s[8]; uint4 u; } pv;
#pragma unroll
    for (int e = 0; e < 8; e++)
      pv.s[e] = vtile[((j & 3) * 16 + hi5 * 8 + e) * 72 + (j >> 2) * 32 + l31];
    *(uint4*)(vd + j * 512 + lane * 8) = pv.u;
  }
}

// ==================== gemm_qkv: 256x256 tile, BK=32, 4-slot ring, counted vmcnt ===
// 512 thr / 8 waves (2M x 4N); per-wave C = 128x64 = acc[8][4] 16x16 frags.
// LDS: 4 slots x (A 16KB + B 16KB) = 128KB; tile t in slot t&3.
// Schedule (2 phases / K-tile, 16 MFMA each):
//   PHASE_A(t): read A-h1(t) frags; issue stage B(t+3); bar; lgkm0; MFMA mhalf0(t);
//               vmcnt(8) [publishes tile t+1 landing]; bar.
//   PHASE_B(t): read B(t+1)+A-h0(t+1) frags; issue stage A(t+4); bar; lgkm0;
//               MFMA mhalf1(t); bar.
// Raw s_barrier (asm, memory clobber) so in-flight global_load_lds survive barriers;
// vmcnt never drained to 0 in steady state (tail: 8 -> 4 -> 0).
// st_16x32 swizzle: within each 16rowx32k 1KB subtile, k ^= ((row>>3)&1)<<4 —
// applied on the gload source address (LDS dest is linear) and on ds_read addrs.

#define VMWAIT(n) asm volatile("s_waitcnt vmcnt(" #n ")" ::: "memory")
#define LGKM0()                                              \
  do {                                                       \
    asm volatile("s_waitcnt lgkmcnt(0)" ::: "memory");       \
    __builtin_amdgcn_sched_barrier(0);                       \
  } while (0)
#define BAR() asm volatile("s_barrier" ::: "memory")

__device__ __forceinline__ void gll16(const u16* g, u16* l) {
  __builtin_amdgcn_global_load_lds((const __attribute__((address_space(1))) unsigned*)g,
                                   (__attribute__((address_space(3))) unsigned*)l, 16, 0, 0);
}

__global__ __launch_bounds__(512, 2) void gemm_qkv(const u16* __restrict__ A,
                                                   const u16* __restrict__ Bt,
                                                   u16* __restrict__ qb,
                                                   u16* __restrict__ kb,
                                                   u16* __restrict__ vb) {
  __shared__ u16 lds[65536];  // 128 KB: slot s at s*16384 (A at +0, B at +8192) u16 units
  int tid = threadIdx.x;
  int w = tid >> 6, lane = tid & 63, l15 = lane & 15, quad = lane >> 4;
  int wr = w >> 2, wc = w & 3;

  // bijective XCD swizzle (384 % 8 == 0); consecutive wgid share the A-panel
  int bid = blockIdx.x;
  int wgid = (bid & 7) * 48 + (bid >> 3);
  int bm = (wgid / 12) * 256;
  int bn3 = (wgid % 12) * 256;

  // ---- staging addresses (per thread: 2 gloads per half-tile; subtile = w*2+c) ----
  int stc0 = w * 2, stc1 = w * 2 + 1;
  int srow = lane >> 2;                              // row within 16-row subtile
  int kswz = ((lane & 3) * 8) ^ ((lane >> 5) << 4);  // inverse-swizzled source k
  const u16* gA0 = A + (size_t)(bm + stc0 * 16 + srow) * 1024 + kswz;
  const u16* gA1 = A + (size_t)(bm + stc1 * 16 + srow) * 1024 + kswz;
  const u16* gB0 = Bt + (size_t)(bn3 + stc0 * 16 + srow) * 1024 + kswz;
  const u16* gB1 = Bt + (size_t)(bn3 + stc1 * 16 + srow) * 1024 + kswz;
  int dA0 = stc0 * 512, dA1 = stc1 * 512;  // LDS dest (u16), wave-uniform

  // ---- fragment read offsets (u16 units, swizzled) ----
  int kq = (quad * 8) ^ ((l15 & 8) << 1);
  int aoffB = wr * 4096 + l15 * 32 + kq;           // + m'*512, m' in [0,8)
  int boffB = 8192 + wc * 2048 + l15 * 32 + kq;    // + n*512,  n in [0,4)

  f32x4 acc[8][4];
#pragma unroll
  for (int m = 0; m < 8; m++)
#pragma unroll
    for (int n = 0; n < 4; n++) acc[m][n] = (f32x4)0.0f;

  short8 a0[4], a1[4], bb0[4], bb1[4];

#define STAGE_A(t)                                     \
  do {                                                 \
    u16* s_ = lds + ((t) & 3) * 16384;                 \
    gll16(gA0 + (t) * 32, s_ + dA0);                   \
    gll16(gA1 + (t) * 32, s_ + dA1);                   \
  } while (0)
#define STAGE_B(t)                                     \
  do {                                                 \
    u16* s_ = lds + ((t) & 3) * 16384 + 8192;          \
    gll16(gB0 + (t) * 32, s_ + dA0);                   \
    gll16(gB1 + (t) * 32, s_ + dA1);                   \
  } while (0)

#define PHASE_A(t, bbcur, DOSTG, VMN)                                                          \
  do {                                                                                         \
    const u16* sl = lds + ((t) & 3) * 16384;                                                   \
    _Pragma("unroll") for (int m = 0; m < 4; m++)                                              \
        a1[m] = *(const short8*)(sl + aoffB + (m + 4) * 512);                                  \
    if (DOSTG) STAGE_B((t) + 3);                                                               \
    BAR();                                                                                     \
    LGKM0();                                                                                   \
    __builtin_amdgcn_s_setprio(1);                                                             \
    _Pragma("unroll") for (int m = 0; m < 4; m++) _Pragma("unroll") for (int n = 0; n < 4; n++) \
        acc[m][n] = __builtin_amdgcn_mfma_f32_16x16x32_bf16(a0[m], bbcur[n], acc[m][n], 0, 0, 0); \
    __builtin_amdgcn_s_setprio(0);                                                             \
    VMN;                                                                                       \
    BAR();                                                                                     \
  } while (0)

#define PHASE_B(t, bbcur, bbnxt, DORD, DOSTG)                                                  \
  do {                                                                                         \
    if (DORD) {                                                                                \
      const u16* sl = lds + (((t) + 1) & 3) * 16384;                                           \
      _Pragma("unroll") for (int n = 0; n < 4; n++)                                            \
          bbnxt[n] = *(const short8*)(sl + boffB + n * 512);                                   \
      _Pragma("unroll") for (int m = 0; m < 4; m++)                                            \
          a0[m] = *(const short8*)(sl + aoffB + m * 512);                                      \
    }                                                                                          \
    if (DOSTG) STAGE_A((t) + 4);                                                               \
    BAR();                                                                                     \
    LGKM0();                                                                                   \
    __builtin_amdgcn_s_setprio(1);                                                             \
    _Pragma("unroll") for (int m = 0; m < 4; m++) _Pragma("unroll") for (int n = 0; n < 4; n++) \
        acc[m + 4][n] =                                                                        \
            __builtin_amdgcn_mfma_f32_16x16x32_bf16(a1[m], bbcur[n], acc[m + 4][n], 0, 0, 0);  \
    __builtin_amdgcn_s_setprio(0);                                                             \
    BAR();                                                                                     \
  } while (0)

  // ---- prologue: stage tiles 0..2 fully + A(3); wait tile 0; pre-read its frags ----
  STAGE_A(0); STAGE_B(0); STAGE_A(1); STAGE_B(1); STAGE_A(2); STAGE_B(2); STAGE_A(3);
  VMWAIT(10);  // 14 issued; oldest 4 (= tile 0) landed
  BAR();
  {
    const u16* sl = lds;  // slot 0
#pragma unroll
    for (int n = 0; n < 4; n++) bb0[n] = *(const short8*)(sl + boffB + n * 512);
#pragma unroll
    for (int m = 0; m < 4; m++) a0[m] = *(const short8*)(sl + aoffB + m * 512);
  }

  // ---- main loop: tiles 0..27 (unroll x2 so bb-parity is static) ----
  for (int t = 0; t < 28; t += 2) {
    PHASE_A(t, bb0, 1, VMWAIT(8));
    PHASE_B(t, bb0, bb1, 1, 1);
    PHASE_A(t + 1, bb1, 1, VMWAIT(8));
    PHASE_B(t + 1, bb1, bb0, 1, 1);
  }
  // ---- tail: tiles 28..31, staging off, vmcnt drains 8 -> 4 -> 0 ----
  PHASE_A(28, bb0, 1, VMWAIT(8));   // stages B(31), waits tile 29
  PHASE_B(28, bb0, bb1, 1, 0);
  PHASE_A(29, bb1, 0, VMWAIT(4));   // waits tile 30
  PHASE_B(29, bb1, bb0, 1, 0);
  PHASE_A(30, bb0, 0, VMWAIT(0));   // waits tile 31 (final drain)
  PHASE_B(30, bb0, bb1, 1, 0);
  PHASE_A(31, bb1, 0, );
  PHASE_B(31, bb1, bb0, 0, 0);

#undef PHASE_A
#undef PHASE_B
#undef STAGE_A
#undef STAGE_B

  // ---- epilogue: q/k/v split; Q pre-scaled by (1/8)*log2(e) for exp2-domain attn ----
  u16* dst = (bn3 < 1024) ? qb : (bn3 < 2048) ? kb : vb;
  float scl = (bn3 < 1024) ? 0.18033688011112f : 1.0f;
  int bnl = bn3 & 1023;
  int rbase = bm + wr * 128 + quad * 4;
  int cbase = bnl + wc * 64 + l15;
#pragma unroll
  for (int m = 0; m < 8; m++)
#pragma unroll
    for (int n = 0; n < 4; n++)
#pragma unroll
      for (int r = 0; r < 4; r++)
        dst[(size_t)(rbase + m * 16 + r) * 1024 + cbase + n * 16] = f2bf(acc[m][n][r] * scl);
}

// ---------------- proj GEMM (m97-style 128x128, unchanged this round) ----------------
#define GEMM_BODY(KSTR)                                                                       \
  __shared__ __align__(16) u16 As[128 * 32];                                                  \
  __shared__ __align__(16) u16 Bs[128 * 32];                                                  \
  int t = threadIdx.x;                                                                        \
  int wave = t >> 6, lane = t & 63, l15 = lane & 15, quad = lane >> 4;                        \
  int bn = blockIdx.x * 128, bm = blockIdx.y * 128;                                           \
  int wm = (wave >> 1) * 64, wn = (wave & 1) * 64;                                            \
  f32x4 acc[4][4];                                                                            \
  for (int i = 0; i < 4; i++)                                                                 \
    for (int j = 0; j < 4; j++) acc[i][j] = (f32x4)0.0f;                                      \
  int srow = wave * 16 + (lane >> 2);                                                         \
  int scol = (lane & 3) * 8;                                                                  \
  const u16* ga0 = A + (size_t)(bm + srow) * KSTR + scol;                                     \
  const u16* ga1 = A + (size_t)(bm + 64 + srow) * KSTR + scol;                                \
  const u16* gb0 = Bt + (size_t)(bn + srow) * KSTR + scol;                                    \
  const u16* gb1 = Bt + (size_t)(bn + 64 + srow) * KSTR + scol;                               \
  u16* lA0 = As + wave * 512;                                                                 \
  u16* lA1 = As + 2048 + wave * 512;                                                          \
  u16* lB0 = Bs + wave * 512;                                                                 \
  u16* lB1 = Bs + 2048 + wave * 512;                                                          \
  for (int k0 = 0; k0 < KSTR; k0 += 32) {                                                     \
    __syncthreads();                                                                          \
    __builtin_amdgcn_global_load_lds((const __attribute__((address_space(1))) unsigned*)(ga0 + k0), \
                                     (__attribute__((address_space(3))) unsigned*)lA0, 16, 0, 0);   \
    __builtin_amdgcn_global_load_lds((const __attribute__((address_space(1))) unsigned*)(ga1 + k0), \
                                     (__attribute__((address_space(3))) unsigned*)lA1, 16, 0, 0);   \
    __builtin_amdgcn_global_load_lds((const __attribute__((address_space(1))) unsigned*)(gb0 + k0), \
                                     (__attribute__((address_space(3))) unsigned*)lB0, 16, 0, 0);   \
    __builtin_amdgcn_global_load_lds((const __attribute__((address_space(1))) unsigned*)(gb1 + k0), \
                                     (__attribute__((address_space(3))) unsigned*)lB1, 16, 0, 0);   \
    __syncthreads();                                                                          \
    short8 a[4], b[4];                                                                        \
    for (int mt = 0; mt < 4; mt++)                                                            \
      a[mt] = *(const short8*)(&As[(wm + mt * 16 + l15) * 32 + quad * 8]);                    \
    for (int nt = 0; nt < 4; nt++)                                                            \
      b[nt] = *(const short8*)(&Bs[(wn + nt * 16 + l15) * 32 + quad * 8]);                    \
    for (int mt = 0; mt < 4; mt++)                                                            \
      for (int nt = 0; nt < 4; nt++)                                                          \
        acc[mt][nt] = __builtin_amdgcn_mfma_f32_16x16x32_bf16(a[mt], b[nt], acc[mt][nt], 0, 0, 0); \
  }

__global__ __launch_bounds__(256) void gemm_proj(const u16* __restrict__ A,
                                                 const u16* __restrict__ Bt,
                                                 float* __restrict__ Co) {
  GEMM_BODY(1024)
#pragma unroll
  for (int mt = 0; mt < 4; mt++)
#pragma unroll
    for (int nt = 0; nt < 4; nt++)
#pragma unroll
      for (int r = 0; r < 4; r++) {
        int row = bm + wm + mt * 16 + quad * 4 + r;
        int col = bn + wn + nt * 16 + l15;
        Co[(size_t)row * 1024 + col] = acc[mt][nt][r];
      }
}

// ---------------- flash attention (unchanged) ----------------
__global__ __launch_bounds__(256, 2) void attn_kernel(const u16* __restrict__ qbuf,
                                                      const u16* __restrict__ kpack,
                                                      const u16* __restrict__ vpack,
                                                      u16* __restrict__ ctx) {
  int t = threadIdx.x;
  int wave = t >> 6, lane = t & 63, l31 = lane & 31, hi = lane >> 5;
  int bh = blockIdx.x;
  int s = (int)blockIdx.y * 4 + wave;
  int b = bh >> 4, h = bh & 15;
  int rowbase = b * 2048;
  int hi4 = hi * 4;

  const u16* kp = kpack + (size_t)bh * (32 * 4096) + lane * 8;
  const u16* vp = vpack + (size_t)bh * (32 * 4096) + lane * 8;

#pragma unroll
  for (int ph = 0; ph < 2; ph++) {
    int strip = ph ? 63 - s : s;
    int q0 = strip * 32;
    int q_lane = q0 + l31;

    const u16* qp = qbuf + (size_t)(rowbase + q_lane) * 1024 + h * 64 + hi * 8;
    short8 qf[4];
#pragma unroll
    for (int ks = 0; ks < 4; ks++) qf[ks] = *(const short8*)(qp + ks * 16);

    float l_run = 0.0f;
    f32x16 o[2];
    o[0] = (f32x16)0.0f; o[1] = (f32x16)0.0f;
    int ktmax = (q0 + 31) >> 6;

    for (int kt = 0; kt <= ktmax; kt++) {
      const u16* kb = kp + kt * 4096;
      const u16* vb = vp + kt * 4096;

      short8 ka[8], vv[8];
#pragma unroll
      for (int j = 0; j < 8; j++) {
        ka[j] = *(const short8*)(kb + j * 512);
        vv[j] = *(const short8*)(vb + j * 512);
      }

      f32x16 st0 = (f32x16)0.0f, st1 = (f32x16)0.0f;
#pragma unroll
      for (int ks = 0; ks < 4; ks++) {
        st0 = __builtin_amdgcn_mfma_f32_32x32x16_bf16(ka[ks], qf[ks], st0, 0, 0, 0);
        st1 = __builtin_amdgcn_mfma_f32_32x32x16_bf16(ka[4 + ks], qf[ks], st1, 0, 0, 0);
      }

      unsigned pk[2][8];
      if (kt == ktmax) {
#pragma unroll
        for (int ii = 0; ii < 8; ii++) {
          int key = kt * 64 + ((2 * ii) & 3) + 8 * ((2 * ii) >> 2) + hi4;
          float p00 = (key     <= q_lane) ? __builtin_amdgcn_exp2f(st0[2 * ii])     : 0.0f;
          float p01 = (key + 1 <= q_lane) ? __builtin_amdgcn_exp2f(st0[2 * ii + 1]) : 0.0f;
          float p10 = (key + 32 <= q_lane) ? __builtin_amdgcn_exp2f(st1[2 * ii])     : 0.0f;
          float p11 = (key + 33 <= q_lane) ? __builtin_amdgcn_exp2f(st1[2 * ii + 1]) : 0.0f;
          l_run += p00 + p01 + p10 + p11;
          pk[0][ii] = ((__float_as_uint(p00) + 0x8000u) >> 16) |
                      ((__float_as_uint(p01) + 0x8000u) & 0xffff0000u);
          pk[1][ii] = ((__float_as_uint(p10) + 0x8000u) >> 16) |
                      ((__float_as_uint(p11) + 0x8000u) & 0xffff0000u);
        }
      } else {
#pragma unroll
        for (int ii = 0; ii < 8; ii++) {
          float p00 = __builtin_amdgcn_exp2f(st0[2 * ii]);
          float p01 = __builtin_amdgcn_exp2f(st0[2 * ii + 1]);
          float p10 = __builtin_amdgcn_exp2f(st1[2 * ii]);
          float p11 = __builtin_amdgcn_exp2f(st1[2 * ii + 1]);
          l_run += p00 + p01 + p10 + p11;
          pk[0][ii] = ((__float_as_uint(p00) + 0x8000u) >> 16) |
                      ((__float_as_uint(p01) + 0x8000u) & 0xffff0000u);
          pk[1][ii] = ((__float_as_uint(p10) + 0x8000u) >> 16) |
                      ((__float_as_uint(p11) + 0x8000u) & 0xffff0000u);
        }
      }

      short8 pf[4];
#pragma unroll
      for (int ks2 = 0; ks2 < 4; ks2++) {
        int km = ks2 >> 1, h4 = (ks2 & 1) * 4;
        unsigned A0 = pk[km][h4 + 0], A1 = pk[km][h4 + 1];
        unsigned B0 = pk[km][h4 + 2], B1 = pk[km][h4 + 3];
        unsigned tA0 = (unsigned)__shfl_xor((int)A0, 32);
        unsigned tA1 = (unsigned)__shfl_xor((int)A1, 32);
        unsigned tB0 = (unsigned)__shfl_xor((int)B0, 32);
        unsigned tB1 = (unsigned)__shfl_xor((int)B1, 32);
        union { unsigned u[4]; short8 sh; } fr;
        fr.u[0] = hi ? tB0 : A0;
        fr.u[1] = hi ? tB1 : A1;
        fr.u[2] = hi ? B0 : tA0;
        fr.u[3] = hi ? B1 : tA1;
        pf[ks2] = fr.sh;
      }

#pragma unroll
      for (int am = 0; am < 2; am++)
#pragma unroll
        for (int ks2 = 0; ks2 < 4; ks2++)
          o[am] = __builtin_amdgcn_mfma_f32_32x32x16_bf16(vv[am * 4 + ks2], pf[ks2], o[am], 0, 0, 0);
    }

    float l_tot = l_run + __shfl_xor(l_run, 32);
    float inv = 1.0f / l_tot;
    size_t obase = (size_t)(rowbase + q_lane) * 1024 + h * 64;
#pragma unroll
    for (int am = 0; am < 2; am++)
#pragma unroll
      for (int k = 0; k < 4; k++) {
        ushort4 w;
        w.x = f2bf(o[am][4 * k + 0] * inv);
        w.y = f2bf(o[am][4 * k + 1] * inv);
        w.z = f2bf(o[am][4 * k + 2] * inv);
        w.w = f2bf(o[am][4 * k + 3] * inv);
        *(ushort4*)&ctx[obase + am * 32 + k * 8 + hi4] = w;
      }
  }
}

// ---------------- launch ----------------
extern "C" void kernel_launch(void* const* d_in, const int* in_sizes, int n_in,
                              void* d_out, int out_size, void* d_ws, size_t ws_size,
                              hipStream_t stream) {
  const float* x      = (const float*)d_in[0];
  const float* w_qkv  = (const float*)d_in[1];
  const float* w_proj = (const float*)d_in[2];
  float* out = (float*)d_out;

  char* ws = (char*)d_ws;
  const size_t MB = 1024 * 1024;
  u16* qbuf   = (u16*)(ws);
  u16* kbuf   = (u16*)(ws + 16 * MB);
  u16* vbuf   = (u16*)(ws + 32 * MB);
  u16* xb     = (u16*)(ws + 48 * MB);
  u16* kpack  = (u16*)(ws + 48 * MB);  // overwrites xb after gemm1
  u16* vpack  = (u16*)(ws + 64 * MB);
  u16* wqkvT  = (u16*)(ws + 80 * MB);
  u16* wprojT = (u16*)(ws + 86 * MB);
  u16* ctx    = kbuf;                  // overwrites kbuf after pack

  cast_kernel<<<8192, 256, 0, stream>>>(x, xb, 2097152);
  tcast_kernel<<<dim3(96, 32), 256, 0, stream>>>(w_qkv, wqkvT, 1024, 3072);
  tcast_kernel<<<dim3(32, 32), 256, 0, stream>>>(w_proj, wprojT, 1024, 1024);

  gemm_qkv<<<dim3(384), 512, 0, stream>>>(xb, wqkvT, qbuf, kbuf, vbuf);
  pack_kv<<<dim3(32, 16, 4), 256, 0, stream>>>(kbuf, vbuf, kpack, vpack);
  attn_kernel<<<dim3(64, 8), 256, 0, stream>>>(qbuf, kpack, vpack, ctx);
  gemm_proj<<<dim3(8, 64), 256, 0, stream>>>(ctx, wprojT, out);
}

// Round 2
// 258.045 us; speedup vs baseline: 1.0006x; 1.0006x over previous
//
#include <hip/hip_runtime.h>
#include <hip/hip_bf16.h>

typedef unsigned short u16;
typedef __attribute__((ext_vector_type(8))) short short8;
typedef __attribute__((ext_vector_type(4))) float f32x4;
typedef __attribute__((ext_vector_type(16))) float f32x16;

__device__ inline u16 f2bf(float f) {
  unsigned u = __float_as_uint(f);
  u += 0x7fffu + ((u >> 16) & 1u);   // round-to-nearest-even
  return (u16)(u >> 16);
}

// ---------------- cast fp32 -> bf16 (vectorized x4) ----------------
__global__ __launch_bounds__(256) void cast_kernel(const float* __restrict__ in,
                                                   u16* __restrict__ out, int n4) {
  int i = blockIdx.x * 256 + threadIdx.x;
  if (i >= n4) return;
  float4 v = ((const float4*)in)[i];
  ushort4 o;
  o.x = f2bf(v.x); o.y = f2bf(v.y); o.z = f2bf(v.z); o.w = f2bf(v.w);
  ((ushort4*)out)[i] = o;
}

// ---------------- transpose-cast: fp32 [K][N] -> bf16 [N][K] ----------------
__global__ __launch_bounds__(256) void tcast_kernel(const float* __restrict__ in,
                                                    u16* __restrict__ out, int K, int N) {
  __shared__ float tile[32][33];
  int bx = blockIdx.x * 32;  // N offset
  int by = blockIdx.y * 32;  // K offset
  int tx = threadIdx.x & 31, ty = threadIdx.x >> 5;
#pragma unroll
  for (int i = 0; i < 4; i++) {
    int r = ty + i * 8;
    tile[r][tx] = in[(size_t)(by + r) * N + bx + tx];
  }
  __syncthreads();
#pragma unroll
  for (int i = 0; i < 4; i++) {
    int r = ty + i * 8;
    out[(size_t)(bx + r) * K + by + tx] = f2bf(tile[tx][r]);
  }
}

// ---------------- pack K,V into fragment-major layout ----------------
__global__ __launch_bounds__(256) void pack_kv(const u16* __restrict__ kbuf,
                                               const u16* __restrict__ vbuf,
                                               u16* __restrict__ kpack,
                                               u16* __restrict__ vpack) {
  __shared__ __align__(16) u16 ktile[64 * 72];
  __shared__ __align__(16) u16 vtile[64 * 72];
  int t = threadIdx.x;
  int kt = blockIdx.x, h = blockIdx.y, b = blockIdx.z;
  int bh = b * 16 + h;
  size_t rb = (size_t)(b * 2048 + kt * 64);
#pragma unroll
  for (int i = 0; i < 2; i++) {
    int idx = i * 256 + t; int r = idx >> 3, c8 = (idx & 7) * 8;
    *(uint4*)&ktile[r * 72 + c8] = *(const uint4*)(kbuf + (rb + r) * 1024 + h * 64 + c8);
    *(uint4*)&vtile[r * 72 + c8] = *(const uint4*)(vbuf + (rb + r) * 1024 + h * 64 + c8);
  }
  __syncthreads();
  u16* kd = kpack + ((size_t)bh * 32 + kt) * 4096;
  u16* vd = vpack + ((size_t)bh * 32 + kt) * 4096;
#pragma unroll
  for (int i = 0; i < 2; i++) {
    int idx = i * 256 + t;
    int j = idx >> 6, lane = idx & 63, l31 = lane & 31, hi5 = lane >> 5;
    *(uint4*)(kd + j * 512 + lane * 8) =
        *(const uint4*)&ktile[((j >> 2) * 32 + l31) * 72 + (j & 3) * 16 + hi5 * 8];
    union { u16 s[8]; uint4 u; } pv;
#pragma unroll
    for (int e = 0; e < 8; e++)
      pv.s[e] = vtile[((j & 3) * 16 + hi5 * 8 + e) * 72 + (j >> 2) * 32 + l31];
    *(uint4*)(vd + j * 512 + lane * 8) = pv.u;
  }
}

// ==================== gemm_qkv: 256x256, BK=32, 4-slot ring, COUNTED waits =========
// 512 thr / 8 waves (2M x 4N); per-wave C = 128x64 = acc[8][4].
// Every phase issues exactly 6 ds_read_b128 and waits lgkmcnt(6): the MFMA cluster
// only waits on the PREVIOUS phase's batch — current-phase reads get a full phase
// plus a barrier of latency cover. Phases are LDS-balanced (6 reads each).
//   PHASE_A(t): read a1(t) x4 + bbnext[0..1] (slot t+1); stage B(t+3);
//               bar; lgkm(6); MFMA m0..3; bar.
//   PHASE_B(t): read bbnext[2..3] + a0(t+1) x4 (slot t+1); stage A(t+4);
//               bar; lgkm(6); MFMA m4..7; vmcnt(6); bar.
// vmcnt(6) at end of B(t) guarantees tiles t+1 AND t+2 fully landed (issue order:
// ... A(t+2)@B(t-2), B(t+2)@A(t-1), A(t+3)@B(t-1), B(t+3)@A(t), A(t+4)@B(t) —
// keeping newest 6 retires everything through B(t+2)). PHASE_A(t+1) reads slot t+2.
// Tail drains 6 -> 4 -> 0. st_16x32 swizzle on gload source + ds_read addrs.

#define VMWAIT(n) asm volatile("s_waitcnt vmcnt(" #n ")" ::: "memory")
#define LGKM(n)                                              \
  do {                                                       \
    asm volatile("s_waitcnt lgkmcnt(" #n ")" ::: "memory");  \
    __builtin_amdgcn_sched_barrier(0);                       \
  } while (0)
#define BAR() asm volatile("s_barrier" ::: "memory")

__device__ __forceinline__ void gll16(const u16* g, u16* l) {
  __builtin_amdgcn_global_load_lds((const __attribute__((address_space(1))) unsigned*)g,
                                   (__attribute__((address_space(3))) unsigned*)l, 16, 0, 0);
}

__global__ __launch_bounds__(512, 2) void gemm_qkv(const u16* __restrict__ A,
                                                   const u16* __restrict__ Bt,
                                                   u16* __restrict__ qb,
                                                   u16* __restrict__ kb,
                                                   u16* __restrict__ vb) {
  __shared__ u16 lds[65536];  // 128 KB: slot s at s*16384 (A at +0, B at +8192) u16 units
  int tid = threadIdx.x;
  int w = tid >> 6, lane = tid & 63, l15 = lane & 15, quad = lane >> 4;
  int wr = w >> 2, wc = w & 3;

  // bijective XCD swizzle (384 % 8 == 0)
  int bid = blockIdx.x;
  int wgid = (bid & 7) * 48 + (bid >> 3);
  int bm = (wgid / 12) * 256;
  int bn3 = (wgid % 12) * 256;

  // ---- staging addresses (per thread: 2 gloads per half-tile; subtile = w*2+c) ----
  int stc0 = w * 2, stc1 = w * 2 + 1;
  int srow = lane >> 2;                              // row within 16-row subtile
  int kswz = ((lane & 3) * 8) ^ ((lane >> 5) << 4);  // inverse-swizzled source k
  const u16* gA0 = A + (size_t)(bm + stc0 * 16 + srow) * 1024 + kswz;
  const u16* gA1 = A + (size_t)(bm + stc1 * 16 + srow) * 1024 + kswz;
  const u16* gB0 = Bt + (size_t)(bn3 + stc0 * 16 + srow) * 1024 + kswz;
  const u16* gB1 = Bt + (size_t)(bn3 + stc1 * 16 + srow) * 1024 + kswz;
  int dA0 = stc0 * 512, dA1 = stc1 * 512;  // LDS dest (u16), wave-uniform

  // ---- fragment read offsets (u16 units, swizzled) ----
  int kq = (quad * 8) ^ ((l15 & 8) << 1);
  int aoffB = wr * 4096 + l15 * 32 + kq;           // + m'*512, m' in [0,8)
  int boffB = 8192 + wc * 2048 + l15 * 32 + kq;    // + n*512,  n in [0,4)

  f32x4 acc[8][4];
#pragma unroll
  for (int m = 0; m < 8; m++)
#pragma unroll
    for (int n = 0; n < 4; n++) acc[m][n] = (f32x4)0.0f;

  short8 a0[4], a1[4], bb0[4], bb1[4];

#define STAGE_A(t)                                     \
  do {                                                 \
    u16* s_ = lds + ((t) & 3) * 16384;                 \
    gll16(gA0 + (t) * 32, s_ + dA0);                   \
    gll16(gA1 + (t) * 32, s_ + dA1);                   \
  } while (0)
#define STAGE_B(t)                                     \
  do {                                                 \
    u16* s_ = lds + ((t) & 3) * 16384 + 8192;          \
    gll16(gB0 + (t) * 32, s_ + dA0);                   \
    gll16(gB1 + (t) * 32, s_ + dA1);                   \
  } while (0)

// PHASE_A(t): MFMA rows 0..63 with (a0, cur); prefetch-read a1(t) + nxt[0..1](t+1).
#define PHASE_A(t, cur, nxt, DONXT, DOSTG)                                                     \
  do {                                                                                         \
    const u16* slA = lds + ((t) & 3) * 16384;                                                  \
    const u16* slN = lds + (((t) + 1) & 3) * 16384;                                            \
    _Pragma("unroll") for (int m = 0; m < 4; m++)                                              \
        a1[m] = *(const short8*)(slA + aoffB + (m + 4) * 512);                                 \
    if (DONXT) {                                                                               \
      nxt[0] = *(const short8*)(slN + boffB + 0 * 512);                                        \
      nxt[1] = *(const short8*)(slN + boffB + 1 * 512);                                        \
    }                                                                                          \
    if (DOSTG) STAGE_B((t) + 3);                                                               \
    BAR();                                                                                     \
    LGKM(6);                                                                                   \
    __builtin_amdgcn_s_setprio(1);                                                             \
    _Pragma("unroll") for (int m = 0; m < 4; m++) _Pragma("unroll") for (int n = 0; n < 4; n++) \
        acc[m][n] = __builtin_amdgcn_mfma_f32_16x16x32_bf16(a0[m], cur[n], acc[m][n], 0, 0, 0); \
    __builtin_amdgcn_s_setprio(0);                                                             \
    BAR();                                                                                     \
  } while (0)

// PHASE_B(t): MFMA rows 64..127 with (a1, cur); prefetch-read nxt[2..3] + a0(t+1).
#define PHASE_B(t, cur, nxt, DORD, DOSTG, WN, VMN)                                             \
  do {                                                                                         \
    if (DORD) {                                                                                \
      const u16* slN = lds + (((t) + 1) & 3) * 16384;                                          \
      nxt[2] = *(const short8*)(slN + boffB + 2 * 512);                                        \
      nxt[3] = *(const short8*)(slN + boffB + 3 * 512);                                        \
      _Pragma("unroll") for (int m = 0; m < 4; m++)                                            \
          a0[m] = *(const short8*)(slN + aoffB + m * 512);                                     \
    }                                                                                          \
    if (DOSTG) STAGE_A((t) + 4);                                                               \
    BAR();                                                                                     \
    LGKM(WN);                                                                                  \
    __builtin_amdgcn_s_setprio(1);                                                             \
    _Pragma("unroll") for (int m = 0; m < 4; m++) _Pragma("unroll") for (int n = 0; n < 4; n++) \
        acc[m + 4][n] =                                                                        \
            __builtin_amdgcn_mfma_f32_16x16x32_bf16(a1[m], cur[n], acc[m + 4][n], 0, 0, 0);    \
    __builtin_amdgcn_s_setprio(0);                                                             \
    VMN;                                                                                       \
    BAR();                                                                                     \
  } while (0)

  // ---- prologue: stage tiles 0..2 fully + A(3); wait tiles 0+1; pre-read tile 0 ----
  STAGE_A(0); STAGE_B(0); STAGE_A(1); STAGE_B(1); STAGE_A(2); STAGE_B(2); STAGE_A(3);
  VMWAIT(6);  // 14 issued; keep 6 -> tiles 0 and 1 fully landed
  BAR();
  {
    const u16* sl = lds;  // slot 0
#pragma unroll
    for (int n = 0; n < 4; n++) bb0[n] = *(const short8*)(sl + boffB + n * 512);
#pragma unroll
    for (int m = 0; m < 4; m++) a0[m] = *(const short8*)(sl + aoffB + m * 512);
  }
  // 8 pre-reads outstanding; A(0)'s lgkm(6) (after issuing its own 6) drains them.

  // ---- main loop: tiles 0..27 (unroll x2 so bb-parity is static) ----
  for (int t = 0; t < 28; t += 2) {
    PHASE_A(t, bb0, bb1, 1, 1);
    PHASE_B(t, bb0, bb1, 1, 1, 6, VMWAIT(6));
    PHASE_A(t + 1, bb1, bb0, 1, 1);
    PHASE_B(t + 1, bb1, bb0, 1, 1, 6, VMWAIT(6));
  }
  // ---- tail: tiles 28..31; B-stage off from 28, A-stage off from 29 ----
  PHASE_A(28, bb0, bb1, 1, 1);                    // stages B(31)
  PHASE_B(28, bb0, bb1, 1, 0, 6, VMWAIT(4));      // tile 30 landed (keep {A31,B31})
  PHASE_A(29, bb1, bb0, 1, 0);
  PHASE_B(29, bb1, bb0, 1, 0, 6, VMWAIT(0));      // tile 31 landed
  PHASE_A(30, bb0, bb1, 1, 0);
  PHASE_B(30, bb0, bb1, 1, 0, 6, (void)0);
  PHASE_A(31, bb1, bb0, 0, 0);                    // issues only 4 reads (a1)
  PHASE_B(31, bb1, bb0, 0, 0, 0, (void)0);        // lgkm(0) drains them

#undef PHASE_A
#undef PHASE_B
#undef STAGE_A
#undef STAGE_B

  // ---- epilogue: q/k/v split; Q pre-scaled by (1/8)*log2(e) for exp2-domain attn ----
  u16* dst = (bn3 < 1024) ? qb : (bn3 < 2048) ? kb : vb;
  float scl = (bn3 < 1024) ? 0.18033688011112f : 1.0f;
  int bnl = bn3 & 1023;
  int rbase = bm + wr * 128 + quad * 4;
  int cbase = bnl + wc * 64 + l15;
#pragma unroll
  for (int m = 0; m < 8; m++)
#pragma unroll
    for (int n = 0; n < 4; n++)
#pragma unroll
      for (int r = 0; r < 4; r++)
        dst[(size_t)(rbase + m * 16 + r) * 1024 + cbase + n * 16] = f2bf(acc[m][n][r] * scl);
}

// ---------------- proj GEMM (m97-style 128x128, unchanged this round) ----------------
#define GEMM_BODY(KSTR)                                                                       \
  __shared__ __align__(16) u16 As[128 * 32];                                                  \
  __shared__ __align__(16) u16 Bs[128 * 32];                                                  \
  int t = threadIdx.x;                                                                        \
  int wave = t >> 6, lane = t & 63, l15 = lane & 15, quad = lane >> 4;                        \
  int bn = blockIdx.x * 128, bm = blockIdx.y * 128;                                           \
  int wm = (wave >> 1) * 64, wn = (wave & 1) * 64;                                            \
  f32x4 acc[4][4];                                                                            \
  for (int i = 0; i < 4; i++)                                                                 \
    for (int j = 0; j < 4; j++) acc[i][j] = (f32x4)0.0f;                                      \
  int srow = wave * 16 + (lane >> 2);                                                         \
  int scol = (lane & 3) * 8;                                                                  \
  const u16* ga0 = A + (size_t)(bm + srow) * KSTR + scol;                                     \
  const u16* ga1 = A + (size_t)(bm + 64 + srow) * KSTR + scol;                                \
  const u16* gb0 = Bt + (size_t)(bn + srow) * KSTR + scol;                                    \
  const u16* gb1 = Bt + (size_t)(bn + 64 + srow) * KSTR + scol;                               \
  u16* lA0 = As + wave * 512;                                                                 \
  u16* lA1 = As + 2048 + wave * 512;                                                          \
  u16* lB0 = Bs + wave * 512;                                                                 \
  u16* lB1 = Bs + 2048 + wave * 512;                                                          \
  for (int k0 = 0; k0 < KSTR; k0 += 32) {                                                     \
    __syncthreads();                                                                          \
    __builtin_amdgcn_global_load_lds((const __attribute__((address_space(1))) unsigned*)(ga0 + k0), \
                                     (__attribute__((address_space(3))) unsigned*)lA0, 16, 0, 0);   \
    __builtin_amdgcn_global_load_lds((const __attribute__((address_space(1))) unsigned*)(ga1 + k0), \
                                     (__attribute__((address_space(3))) unsigned*)lA1, 16, 0, 0);   \
    __builtin_amdgcn_global_load_lds((const __attribute__((address_space(1))) unsigned*)(gb0 + k0), \
                                     (__attribute__((address_space(3))) unsigned*)lB0, 16, 0, 0);   \
    __builtin_amdgcn_global_load_lds((const __attribute__((address_space(1))) unsigned*)(gb1 + k0), \
                                     (__attribute__((address_space(3))) unsigned*)lB1, 16, 0, 0);   \
    __syncthreads();                                                                          \
    short8 a[4], b[4];                                                                        \
    for (int mt = 0; mt < 4; mt++)                                                            \
      a[mt] = *(const short8*)(&As[(wm + mt * 16 + l15) * 32 + quad * 8]);                    \
    for (int nt = 0; nt < 4; nt++)                                                            \
      b[nt] = *(const short8*)(&Bs[(wn + nt * 16 + l15) * 32 + quad * 8]);                    \
    for (int mt = 0; mt < 4; mt++)                                                            \
      for (int nt = 0; nt < 4; nt++)                                                          \
        acc[mt][nt] = __builtin_amdgcn_mfma_f32_16x16x32_bf16(a[mt], b[nt], acc[mt][nt], 0, 0, 0); \
  }

__global__ __launch_bounds__(256) void gemm_proj(const u16* __restrict__ A,
                                                 const u16* __restrict__ Bt,
                                                 float* __restrict__ Co) {
  GEMM_BODY(1024)
#pragma unroll
  for (int mt = 0; mt < 4; mt++)
#pragma unroll
    for (int nt = 0; nt < 4; nt++)
#pragma unroll
      for (int r = 0; r < 4; r++) {
        int row = bm + wm + mt * 16 + quad * 4 + r;
        int col = bn + wn + nt * 16 + l15;
        Co[(size_t)row * 1024 + col] = acc[mt][nt][r];
      }
}

// ---------------- flash attention (unchanged) ----------------
__global__ __launch_bounds__(256, 2) void attn_kernel(const u16* __restrict__ qbuf,
                                                      const u16* __restrict__ kpack,
                                                      const u16* __restrict__ vpack,
                                                      u16* __restrict__ ctx) {
  int t = threadIdx.x;
  int wave = t >> 6, lane = t & 63, l31 = lane & 31, hi = lane >> 5;
  int bh = blockIdx.x;
  int s = (int)blockIdx.y * 4 + wave;
  int b = bh >> 4, h = bh & 15;
  int rowbase = b * 2048;
  int hi4 = hi * 4;

  const u16* kp = kpack + (size_t)bh * (32 * 4096) + lane * 8;
  const u16* vp = vpack + (size_t)bh * (32 * 4096) + lane * 8;

#pragma unroll
  for (int ph = 0; ph < 2; ph++) {
    int strip = ph ? 63 - s : s;
    int q0 = strip * 32;
    int q_lane = q0 + l31;

    const u16* qp = qbuf + (size_t)(rowbase + q_lane) * 1024 + h * 64 + hi * 8;
    short8 qf[4];
#pragma unroll
    for (int ks = 0; ks < 4; ks++) qf[ks] = *(const short8*)(qp + ks * 16);

    float l_run = 0.0f;
    f32x16 o[2];
    o[0] = (f32x16)0.0f; o[1] = (f32x16)0.0f;
    int ktmax = (q0 + 31) >> 6;

    for (int kt = 0; kt <= ktmax; kt++) {
      const u16* kb = kp + kt * 4096;
      const u16* vb = vp + kt * 4096;

      short8 ka[8], vv[8];
#pragma unroll
      for (int j = 0; j < 8; j++) {
        ka[j] = *(const short8*)(kb + j * 512);
        vv[j] = *(const short8*)(vb + j * 512);
      }

      f32x16 st0 = (f32x16)0.0f, st1 = (f32x16)0.0f;
#pragma unroll
      for (int ks = 0; ks < 4; ks++) {
        st0 = __builtin_amdgcn_mfma_f32_32x32x16_bf16(ka[ks], qf[ks], st0, 0, 0, 0);
        st1 = __builtin_amdgcn_mfma_f32_32x32x16_bf16(ka[4 + ks], qf[ks], st1, 0, 0, 0);
      }

      unsigned pk[2][8];
      if (kt == ktmax) {
#pragma unroll
        for (int ii = 0; ii < 8; ii++) {
          int key = kt * 64 + ((2 * ii) & 3) + 8 * ((2 * ii) >> 2) + hi4;
          float p00 = (key     <= q_lane) ? __builtin_amdgcn_exp2f(st0[2 * ii])     : 0.0f;
          float p01 = (key + 1 <= q_lane) ? __builtin_amdgcn_exp2f(st0[2 * ii + 1]) : 0.0f;
          float p10 = (key + 32 <= q_lane) ? __builtin_amdgcn_exp2f(st1[2 * ii])     : 0.0f;
          float p11 = (key + 33 <= q_lane) ? __builtin_amdgcn_exp2f(st1[2 * ii + 1]) : 0.0f;
          l_run += p00 + p01 + p10 + p11;
          pk[0][ii] = ((__float_as_uint(p00) + 0x8000u) >> 16) |
                      ((__float_as_uint(p01) + 0x8000u) & 0xffff0000u);
          pk[1][ii] = ((__float_as_uint(p10) + 0x8000u) >> 16) |
                      ((__float_as_uint(p11) + 0x8000u) & 0xffff0000u);
        }
      } else {
#pragma unroll
        for (int ii = 0; ii < 8; ii++) {
          float p00 = __builtin_amdgcn_exp2f(st0[2 * ii]);
          float p01 = __builtin_amdgcn_exp2f(st0[2 * ii + 1]);
          float p10 = __builtin_amdgcn_exp2f(st1[2 * ii]);
          float p11 = __builtin_amdgcn_exp2f(st1[2 * ii + 1]);
          l_run += p00 + p01 + p10 + p11;
          pk[0][ii] = ((__float_as_uint(p00) + 0x8000u) >> 16) |
                      ((__float_as_uint(p01) + 0x8000u) & 0xffff0000u);
          pk[1][ii] = ((__float_as_uint(p10) + 0x8000u) >> 16) |
                      ((__float_as_uint(p11) + 0x8000u) & 0xffff0000u);
        }
      }

      short8 pf[4];
#pragma unroll
      for (int ks2 = 0; ks2 < 4; ks2++) {
        int km = ks2 >> 1, h4 = (ks2 & 1) * 4;
        unsigned A0 = pk[km][h4 + 0], A1 = pk[km][h4 + 1];
        unsigned B0 = pk[km][h4 + 2], B1 = pk[km][h4 + 3];
        unsigned tA0 = (unsigned)__shfl_xor((int)A0, 32);
        unsigned tA1 = (unsigned)__shfl_xor((int)A1, 32);
        unsigned tB0 = (unsigned)__shfl_xor((int)B0, 32);
        unsigned tB1 = (unsigned)__shfl_xor((int)B1, 32);
        union { unsigned u[4]; short8 sh; } fr;
        fr.u[0] = hi ? tB0 : A0;
        fr.u[1] = hi ? tB1 : A1;
        fr.u[2] = hi ? B0 : tA0;
        fr.u[3] = hi ? B1 : tA1;
        pf[ks2] = fr.sh;
      }

#pragma unroll
      for (int am = 0; am < 2; am++)
#pragma unroll
        for (int ks2 = 0; ks2 < 4; ks2++)
          o[am] = __builtin_amdgcn_mfma_f32_32x32x16_bf16(vv[am * 4 + ks2], pf[ks2], o[am], 0, 0, 0);
    }

    float l_tot = l_run + __shfl_xor(l_run, 32);
    float inv = 1.0f / l_tot;
    size_t obase = (size_t)(rowbase + q_lane) * 1024 + h * 64;
#pragma unroll
    for (int am = 0; am < 2; am++)
#pragma unroll
      for (int k = 0; k < 4; k++) {
        ushort4 w;
        w.x = f2bf(o[am][4 * k + 0] * inv);
        w.y = f2bf(o[am][4 * k + 1] * inv);
        w.z = f2bf(o[am][4 * k + 2] * inv);
        w.w = f2bf(o[am][4 * k + 3] * inv);
        *(ushort4*)&ctx[obase + am * 32 + k * 8 + hi4] = w;
      }
  }
}

// ---------------- launch ----------------
extern "C" void kernel_launch(void* const* d_in, const int* in_sizes, int n_in,
                              void* d_out, int out_size, void* d_ws, size_t ws_size,
                              hipStream_t stream) {
  const float* x      = (const float*)d_in[0];
  const float* w_qkv  = (const float*)d_in[1];
  const float* w_proj = (const float*)d_in[2];
  float* out = (float*)d_out;

  char* ws = (char*)d_ws;
  const size_t MB = 1024 * 1024;
  u16* qbuf   = (u16*)(ws);
  u16* kbuf   = (u16*)(ws + 16 * MB);
  u16* vbuf   = (u16*)(ws + 32 * MB);
  u16* xb     = (u16*)(ws + 48 * MB);
  u16* kpack  = (u16*)(ws + 48 * MB);  // overwrites xb after gemm1
  u16* vpack  = (u16*)(ws + 64 * MB);
  u16* wqkvT  = (u16*)(ws + 80 * MB);
  u16* wprojT = (u16*)(ws + 86 * MB);
  u16* ctx    = kbuf;                  // overwrites kbuf after pack

  cast_kernel<<<8192, 256, 0, stream>>>(x, xb, 2097152);
  tcast_kernel<<<dim3(96, 32), 256, 0, stream>>>(w_qkv, wqkvT, 1024, 3072);
  tcast_kernel<<<dim3(32, 32), 256, 0, stream>>>(w_proj, wprojT, 1024, 1024);

  gemm_qkv<<<dim3(384), 512, 0, stream>>>(xb, wqkvT, qbuf, kbuf, vbuf);
  pack_kv<<<dim3(32, 16, 4), 256, 0, stream>>>(kbuf, vbuf, kpack, vpack);
  attn_kernel<<<dim3(64, 8), 256, 0, stream>>>(qbuf, kpack, vpack, ctx);
  gemm_proj<<<dim3(8, 64), 256, 0, stream>>>(ctx, wprojT, out);
}

// Round 3
// 254.444 us; speedup vs baseline: 1.0148x; 1.0142x over previous
//
#include <hip/hip_runtime.h>
#include <hip/hip_bf16.h>

typedef unsigned short u16;
typedef __attribute__((ext_vector_type(8))) short short8;
typedef __attribute__((ext_vector_type(4))) float f32x4;
typedef __attribute__((ext_vector_type(16))) float f32x16;

__device__ inline u16 f2bf(float f) {
  unsigned u = __float_as_uint(f);
  u += 0x7fffu + ((u >> 16) & 1u);   // round-to-nearest-even
  return (u16)(u >> 16);
}

// ---------------- cast fp32 -> bf16 (vectorized x4) ----------------
__global__ __launch_bounds__(256) void cast_kernel(const float* __restrict__ in,
                                                   u16* __restrict__ out, int n4) {
  int i = blockIdx.x * 256 + threadIdx.x;
  if (i >= n4) return;
  float4 v = ((const float4*)in)[i];
  ushort4 o;
  o.x = f2bf(v.x); o.y = f2bf(v.y); o.z = f2bf(v.z); o.w = f2bf(v.w);
  ((ushort4*)out)[i] = o;
}

// ---------------- transpose-cast: fp32 [K][N] -> bf16 [N][K] ----------------
__global__ __launch_bounds__(256) void tcast_kernel(const float* __restrict__ in,
                                                    u16* __restrict__ out, int K, int N) {
  __shared__ float tile[32][33];
  int bx = blockIdx.x * 32;  // N offset
  int by = blockIdx.y * 32;  // K offset
  int tx = threadIdx.x & 31, ty = threadIdx.x >> 5;
#pragma unroll
  for (int i = 0; i < 4; i++) {
    int r = ty + i * 8;
    tile[r][tx] = in[(size_t)(by + r) * N + bx + tx];
  }
  __syncthreads();
#pragma unroll
  for (int i = 0; i < 4; i++) {
    int r = ty + i * 8;
    out[(size_t)(bx + r) * K + by + tx] = f2bf(tile[tx][r]);
  }
}

// ---------------- pack K,V into fragment-major layout ----------------
__global__ __launch_bounds__(256) void pack_kv(const u16* __restrict__ kbuf,
                                               const u16* __restrict__ vbuf,
                                               u16* __restrict__ kpack,
                                               u16* __restrict__ vpack) {
  __shared__ __align__(16) u16 ktile[64 * 72];
  __shared__ __align__(16) u16 vtile[64 * 72];
  int t = threadIdx.x;
  int kt = blockIdx.x, h = blockIdx.y, b = blockIdx.z;
  int bh = b * 16 + h;
  size_t rb = (size_t)(b * 2048 + kt * 64);
#pragma unroll
  for (int i = 0; i < 2; i++) {
    int idx = i * 256 + t; int r = idx >> 3, c8 = (idx & 7) * 8;
    *(uint4*)&ktile[r * 72 + c8] = *(const uint4*)(kbuf + (rb + r) * 1024 + h * 64 + c8);
    *(uint4*)&vtile[r * 72 + c8] = *(const uint4*)(vbuf + (rb + r) * 1024 + h * 64 + c8);
  }
  __syncthreads();
  u16* kd = kpack + ((size_t)bh * 32 + kt) * 4096;
  u16* vd = vpack + ((size_t)bh * 32 + kt) * 4096;
#pragma unroll
  for (int i = 0; i < 2; i++) {
    int idx = i * 256 + t;
    int j = idx >> 6, lane = idx & 63, l31 = lane & 31, hi5 = lane >> 5;
    *(uint4*)(kd + j * 512 + lane * 8) =
        *(const uint4*)&ktile[((j >> 2) * 32 + l31) * 72 + (j & 3) * 16 + hi5 * 8];
    union { u16 s[8]; uint4 u; } pv;
#pragma unroll
    for (int e = 0; e < 8; e++)
      pv.s[e] = vtile[((j & 3) * 16 + hi5 * 8 + e) * 72 + (j >> 2) * 32 + l31];
    *(uint4*)(vd + j * 512 + lane * 8) = pv.u;
  }
}

// ==================== gemm_qkv: 256x256, BK=64, m201-faithful 8-phase ==============
// 512 thr / 8 waves (2M x 4N); per-wave C = 128x64 = acc[8][4] 16x16 frags.
// LDS: 2 K-tile buffers x 64KB = 128KB. Buffer = [Ah0|Ah1|Bh0|Bh1], half = 128x64
// stored as 2 k-subs of [128 rows][32 k] (8KB each, 1 gload/thread per sub).
// 4 phases per K-tile (K=64):
//   P1(T): read a@s0 (8);      stage Ah0(T+1); bar; lgkm0; MFMA m*n01@s0; bar
//   P2(T): read bB=b@s1 (4);   stage Ah1(T+1); bar; lgkm0; MFMA m*n23@s0; bar
//   P3(T): read a@s1 (8);      stage Bh0(T+2); bar; lgkm0; MFMA m*n01@s1; vm(6); bar
//   P4(T): read bA=b@s0(T+1)(4) stage Bh1(T+2); bar; lgkm0; MFMA m*n23@s1; vm(4); bar
// vm(6)@P3 retires Bh0/Bh1(T+1) (published by P3's bar, consumed by P4's read);
// vm(4)@P4 retires Ah0/Ah1(T+1) (consumed by P1(T+1)). Never 0 in steady state.
// Buffer WAR safe: every overwrite of buffer(T) issues >=1 phase after that region's
// last ds_read completed at its phase's lgkm0. st_16x32 swizzle on gload source +
// ds_read addrs (verified conflict-free, SQ_LDS_BANK_CONFLICT = 0).

#define VMWAIT(n) asm volatile("s_waitcnt vmcnt(" #n ")" ::: "memory")
#define LGKM0()                                              \
  do {                                                       \
    asm volatile("s_waitcnt lgkmcnt(0)" ::: "memory");       \
    __builtin_amdgcn_sched_barrier(0);                       \
  } while (0)
#define BAR() asm volatile("s_barrier" ::: "memory")

__device__ __forceinline__ void gll16(const u16* g, u16* l) {
  __builtin_amdgcn_global_load_lds((const __attribute__((address_space(1))) unsigned*)g,
                                   (__attribute__((address_space(3))) unsigned*)l, 16, 0, 0);
}

__global__ __launch_bounds__(512, 2) void gemm_qkv(const u16* __restrict__ A,
                                                   const u16* __restrict__ Bt,
                                                   u16* __restrict__ qb,
                                                   u16* __restrict__ kb,
                                                   u16* __restrict__ vb) {
  __shared__ u16 lds[65536];  // 128 KB: buffer b at b*32768 u16
  int tid = threadIdx.x;
  int w = tid >> 6, lane = tid & 63, l15 = lane & 15, quad = lane >> 4;
  int wr = w >> 2, wc = w & 3;

  // bijective XCD swizzle (384 % 8 == 0)
  int bid = blockIdx.x;
  int wgid = (bid & 7) * 48 + (bid >> 3);
  int bm = (wgid / 12) * 256;
  int bn3 = (wgid % 12) * 256;

  // ---- staging addresses: per gload, wave w covers 16 rows x 32 k of one k-sub ----
  int srow = lane >> 2;                              // row within 16-row subtile
  int kswz = ((lane & 3) * 8) ^ ((lane >> 5) << 4);  // inverse-swizzled source k (u16)
  const u16* gA0 = A + (size_t)(bm + w * 16 + srow) * 1024 + kswz;
  const u16* gA1 = A + (size_t)(bm + 128 + w * 16 + srow) * 1024 + kswz;
  const u16* gB0 = Bt + (size_t)(bn3 + w * 16 + srow) * 1024 + kswz;
  const u16* gB1 = Bt + (size_t)(bn3 + 128 + w * 16 + srow) * 1024 + kswz;

  // ---- fragment read offsets (u16 units, swizzled); + m*512 / n*512, + s*4096 ----
  int kq = (quad * 8) ^ ((l15 & 8) << 1);
  int aoff = wr * 8192 + l15 * 32 + kq;                         // within A-half pair
  int boff = 16384 + (wc >> 1) * 8192 + (wc & 1) * 2048 + l15 * 32 + kq;

  f32x4 acc[8][4];
#pragma unroll
  for (int m = 0; m < 8; m++)
#pragma unroll
    for (int n = 0; n < 4; n++) acc[m][n] = (f32x4)0.0f;

  short8 a[8], bA[4], bB[4];

#define STAGE_AH0(T)                                          \
  do {                                                        \
    u16* d_ = lds + ((T) & 1) * 32768 + w * 512;              \
    gll16(gA0 + (size_t)(T) * 64, d_);                        \
    gll16(gA0 + (size_t)(T) * 64 + 32, d_ + 4096);            \
  } while (0)
#define STAGE_AH1(T)                                          \
  do {                                                        \
    u16* d_ = lds + ((T) & 1) * 32768 + 8192 + w * 512;       \
    gll16(gA1 + (size_t)(T) * 64, d_);                        \
    gll16(gA1 + (size_t)(T) * 64 + 32, d_ + 4096);            \
  } while (0)
#define STAGE_BH0(T)                                          \
  do {                                                        \
    u16* d_ = lds + ((T) & 1) * 32768 + 16384 + w * 512;      \
    gll16(gB0 + (size_t)(T) * 64, d_);                        \
    gll16(gB0 + (size_t)(T) * 64 + 32, d_ + 4096);            \
  } while (0)
#define STAGE_BH1(T)                                          \
  do {                                                        \
    u16* d_ = lds + ((T) & 1) * 32768 + 24576 + w * 512;      \
    gll16(gB1 + (size_t)(T) * 64, d_);                        \
    gll16(gB1 + (size_t)(T) * 64 + 32, d_ + 4096);            \
  } while (0)

#define MFMA16(NLO, BV0, BV1)                                                                  \
  do {                                                                                         \
    __builtin_amdgcn_s_setprio(1);                                                             \
    _Pragma("unroll") for (int m = 0; m < 8; m++)                                              \
        acc[m][NLO] = __builtin_amdgcn_mfma_f32_16x16x32_bf16(a[m], BV0, acc[m][NLO], 0, 0, 0);\
    _Pragma("unroll") for (int m = 0; m < 8; m++)                                              \
        acc[m][NLO + 1] =                                                                      \
            __builtin_amdgcn_mfma_f32_16x16x32_bf16(a[m], BV1, acc[m][NLO + 1], 0, 0, 0);      \
    __builtin_amdgcn_s_setprio(0);                                                             \
  } while (0)

#define PHASE1(T, DOSTG)                                                                       \
  do {                                                                                         \
    const u16* bc_ = lds + ((T) & 1) * 32768;                                                  \
    _Pragma("unroll") for (int m = 0; m < 8; m++)                                              \
        a[m] = *(const short8*)(bc_ + aoff + m * 512);                                         \
    if (DOSTG) STAGE_AH0((T) + 1);                                                             \
    BAR(); LGKM0();                                                                            \
    MFMA16(0, bA[0], bA[1]);                                                                   \
    BAR();                                                                                     \
  } while (0)

#define PHASE2(T, DOSTG)                                                                       \
  do {                                                                                         \
    const u16* bc_ = lds + ((T) & 1) * 32768;                                                  \
    _Pragma("unroll") for (int n = 0; n < 4; n++)                                              \
        bB[n] = *(const short8*)(bc_ + boff + 4096 + n * 512);                                 \
    if (DOSTG) STAGE_AH1((T) + 1);                                                             \
    BAR(); LGKM0();                                                                            \
    MFMA16(2, bA[2], bA[3]);                                                                   \
    BAR();                                                                                     \
  } while (0)

#define PHASE3(T, DOSTG, VMN)                                                                  \
  do {                                                                                         \
    const u16* bc_ = lds + ((T) & 1) * 32768;                                                  \
    _Pragma("unroll") for (int m = 0; m < 8; m++)                                              \
        a[m] = *(const short8*)(bc_ + aoff + 4096 + m * 512);                                  \
    if (DOSTG) STAGE_BH0((T) + 2);                                                             \
    BAR(); LGKM0();                                                                            \
    MFMA16(0, bB[0], bB[1]);                                                                   \
    VMN;                                                                                       \
    BAR();                                                                                     \
  } while (0)

#define PHASE4(T, DORD, DOSTG, VMN)                                                            \
  do {                                                                                         \
    if (DORD) {                                                                                \
      const u16* bn_ = lds + (((T) + 1) & 1) * 32768;                                          \
      _Pragma("unroll") for (int n = 0; n < 4; n++)                                            \
          bA[n] = *(const short8*)(bn_ + boff + n * 512);                                      \
    }                                                                                          \
    if (DOSTG) STAGE_BH1((T) + 2);                                                             \
    BAR(); LGKM0();                                                                            \
    MFMA16(2, bB[2], bB[3]);                                                                   \
    VMN;                                                                                       \
    BAR();                                                                                     \
  } while (0)

  // ---- prologue: B(0), A(0), B(1); retire B(0)+A(0); pre-read bA = b@s0(0) ----
  STAGE_BH0(0); STAGE_BH1(0); STAGE_AH0(0); STAGE_AH1(0); STAGE_BH0(1); STAGE_BH1(1);
  VMWAIT(4);  // 12 issued; keep B(1)'s 4 in flight
  BAR();
  {
    const u16* bc_ = lds;  // buffer 0
#pragma unroll
    for (int n = 0; n < 4; n++) bA[n] = *(const short8*)(bc_ + boff + n * 512);
  }

  // ---- main loop: K-tiles 0..13 uniform ----
  for (int T = 0; T < 14; ++T) {
    PHASE1(T, 1);
    PHASE2(T, 1);
    PHASE3(T, 1, VMWAIT(6));
    PHASE4(T, 1, 1, VMWAIT(4));
  }
  // ---- tail: T=14 (B-stage off), T=15 (all off, drained) ----
  PHASE1(14, 1);
  PHASE2(14, 1);
  PHASE3(14, 0, VMWAIT(4));   // retire B(15); keep A(15)
  PHASE4(14, 1, 0, VMWAIT(0));  // retire A(15)
  PHASE1(15, 0);
  PHASE2(15, 0);
  PHASE3(15, 0, (void)0);
  PHASE4(15, 0, 0, (void)0);

#undef PHASE1
#undef PHASE2
#undef PHASE3
#undef PHASE4
#undef MFMA16
#undef STAGE_AH0
#undef STAGE_AH1
#undef STAGE_BH0
#undef STAGE_BH1

  // ---- epilogue: q/k/v split; Q pre-scaled by (1/8)*log2(e) for exp2-domain attn ----
  u16* dst = (bn3 < 1024) ? qb : (bn3 < 2048) ? kb : vb;
  float scl = (bn3 < 1024) ? 0.18033688011112f : 1.0f;
  int bnl = bn3 & 1023;
  int rbase = bm + wr * 128 + quad * 4;
  int cbase = bnl + wc * 64 + l15;
#pragma unroll
  for (int m = 0; m < 8; m++)
#pragma unroll
    for (int n = 0; n < 4; n++)
#pragma unroll
      for (int r = 0; r < 4; r++)
        dst[(size_t)(rbase + m * 16 + r) * 1024 + cbase + n * 16] = f2bf(acc[m][n][r] * scl);
}

// ---------------- proj GEMM (m97-style 128x128, unchanged this round) ----------------
#define GEMM_BODY(KSTR)                                                                       \
  __shared__ __align__(16) u16 As[128 * 32];                                                  \
  __shared__ __align__(16) u16 Bs[128 * 32];                                                  \
  int t = threadIdx.x;                                                                        \
  int wave = t >> 6, lane = t & 63, l15 = lane & 15, quad = lane >> 4;                        \
  int bn = blockIdx.x * 128, bm = blockIdx.y * 128;                                           \
  int wm = (wave >> 1) * 64, wn = (wave & 1) * 64;                                            \
  f32x4 acc[4][4];                                                                            \
  for (int i = 0; i < 4; i++)                                                                 \
    for (int j = 0; j < 4; j++) acc[i][j] = (f32x4)0.0f;                                      \
  int srow = wave * 16 + (lane >> 2);                                                         \
  int scol = (lane & 3) * 8;                                                                  \
  const u16* ga0 = A + (size_t)(bm + srow) * KSTR + scol;                                     \
  const u16* ga1 = A + (size_t)(bm + 64 + srow) * KSTR + scol;                                \
  const u16* gb0 = Bt + (size_t)(bn + srow) * KSTR + scol;                                    \
  const u16* gb1 = Bt + (size_t)(bn + 64 + srow) * KSTR + scol;                               \
  u16* lA0 = As + wave * 512;                                                                 \
  u16* lA1 = As + 2048 + wave * 512;                                                          \
  u16* lB0 = Bs + wave * 512;                                                                 \
  u16* lB1 = Bs + 2048 + wave * 512;                                                          \
  for (int k0 = 0; k0 < KSTR; k0 += 32) {                                                     \
    __syncthreads();                                                                          \
    __builtin_amdgcn_global_load_lds((const __attribute__((address_space(1))) unsigned*)(ga0 + k0), \
                                     (__attribute__((address_space(3))) unsigned*)lA0, 16, 0, 0);   \
    __builtin_amdgcn_global_load_lds((const __attribute__((address_space(1))) unsigned*)(ga1 + k0), \
                                     (__attribute__((address_space(3))) unsigned*)lA1, 16, 0, 0);   \
    __builtin_amdgcn_global_load_lds((const __attribute__((address_space(1))) unsigned*)(gb0 + k0), \
                                     (__attribute__((address_space(3))) unsigned*)lB0, 16, 0, 0);   \
    __builtin_amdgcn_global_load_lds((const __attribute__((address_space(1))) unsigned*)(gb1 + k0), \
                                     (__attribute__((address_space(3))) unsigned*)lB1, 16, 0, 0);   \
    __syncthreads();                                                                          \
    short8 a[4], b[4];                                                                        \
    for (int mt = 0; mt < 4; mt++)                                                            \
      a[mt] = *(const short8*)(&As[(wm + mt * 16 + l15) * 32 + quad * 8]);                    \
    for (int nt = 0; nt < 4; nt++)                                                            \
      b[nt] = *(const short8*)(&Bs[(wn + nt * 16 + l15) * 32 + quad * 8]);                    \
    for (int mt = 0; mt < 4; mt++)                                                            \
      for (int nt = 0; nt < 4; nt++)                                                          \
        acc[mt][nt] = __builtin_amdgcn_mfma_f32_16x16x32_bf16(a[mt], b[nt], acc[mt][nt], 0, 0, 0); \
  }

__global__ __launch_bounds__(256) void gemm_proj(const u16* __restrict__ A,
                                                 const u16* __restrict__ Bt,
                                                 float* __restrict__ Co) {
  GEMM_BODY(1024)
#pragma unroll
  for (int mt = 0; mt < 4; mt++)
#pragma unroll
    for (int nt = 0; nt < 4; nt++)
#pragma unroll
      for (int r = 0; r < 4; r++) {
        int row = bm + wm + mt * 16 + quad * 4 + r;
        int col = bn + wn + nt * 16 + l15;
        Co[(size_t)row * 1024 + col] = acc[mt][nt][r];
      }
}

// ---------------- flash attention (unchanged) ----------------
__global__ __launch_bounds__(256, 2) void attn_kernel(const u16* __restrict__ qbuf,
                                                      const u16* __restrict__ kpack,
                                                      const u16* __restrict__ vpack,
                                                      u16* __restrict__ ctx) {
  int t = threadIdx.x;
  int wave = t >> 6, lane = t & 63, l31 = lane & 31, hi = lane >> 5;
  int bh = blockIdx.x;
  int s = (int)blockIdx.y * 4 + wave;
  int b = bh >> 4, h = bh & 15;
  int rowbase = b * 2048;
  int hi4 = hi * 4;

  const u16* kp = kpack + (size_t)bh * (32 * 4096) + lane * 8;
  const u16* vp = vpack + (size_t)bh * (32 * 4096) + lane * 8;

#pragma unroll
  for (int ph = 0; ph < 2; ph++) {
    int strip = ph ? 63 - s : s;
    int q0 = strip * 32;
    int q_lane = q0 + l31;

    const u16* qp = qbuf + (size_t)(rowbase + q_lane) * 1024 + h * 64 + hi * 8;
    short8 qf[4];
#pragma unroll
    for (int ks = 0; ks < 4; ks++) qf[ks] = *(const short8*)(qp + ks * 16);

    float l_run = 0.0f;
    f32x16 o[2];
    o[0] = (f32x16)0.0f; o[1] = (f32x16)0.0f;
    int ktmax = (q0 + 31) >> 6;

    for (int kt = 0; kt <= ktmax; kt++) {
      const u16* kb = kp + kt * 4096;
      const u16* vb = vp + kt * 4096;

      short8 ka[8], vv[8];
#pragma unroll
      for (int j = 0; j < 8; j++) {
        ka[j] = *(const short8*)(kb + j * 512);
        vv[j] = *(const short8*)(vb + j * 512);
      }

      f32x16 st0 = (f32x16)0.0f, st1 = (f32x16)0.0f;
#pragma unroll
      for (int ks = 0; ks < 4; ks++) {
        st0 = __builtin_amdgcn_mfma_f32_32x32x16_bf16(ka[ks], qf[ks], st0, 0, 0, 0);
        st1 = __builtin_amdgcn_mfma_f32_32x32x16_bf16(ka[4 + ks], qf[ks], st1, 0, 0, 0);
      }

      unsigned pk[2][8];
      if (kt == ktmax) {
#pragma unroll
        for (int ii = 0; ii < 8; ii++) {
          int key = kt * 64 + ((2 * ii) & 3) + 8 * ((2 * ii) >> 2) + hi4;
          float p00 = (key     <= q_lane) ? __builtin_amdgcn_exp2f(st0[2 * ii])     : 0.0f;
          float p01 = (key + 1 <= q_lane) ? __builtin_amdgcn_exp2f(st0[2 * ii + 1]) : 0.0f;
          float p10 = (key + 32 <= q_lane) ? __builtin_amdgcn_exp2f(st1[2 * ii])     : 0.0f;
          float p11 = (key + 33 <= q_lane) ? __builtin_amdgcn_exp2f(st1[2 * ii + 1]) : 0.0f;
          l_run += p00 + p01 + p10 + p11;
          pk[0][ii] = ((__float_as_uint(p00) + 0x8000u) >> 16) |
                      ((__float_as_uint(p01) + 0x8000u) & 0xffff0000u);
          pk[1][ii] = ((__float_as_uint(p10) + 0x8000u) >> 16) |
                      ((__float_as_uint(p11) + 0x8000u) & 0xffff0000u);
        }
      } else {
#pragma unroll
        for (int ii = 0; ii < 8; ii++) {
          float p00 = __builtin_amdgcn_exp2f(st0[2 * ii]);
          float p01 = __builtin_amdgcn_exp2f(st0[2 * ii + 1]);
          float p10 = __builtin_amdgcn_exp2f(st1[2 * ii]);
          float p11 = __builtin_amdgcn_exp2f(st1[2 * ii + 1]);
          l_run += p00 + p01 + p10 + p11;
          pk[0][ii] = ((__float_as_uint(p00) + 0x8000u) >> 16) |
                      ((__float_as_uint(p01) + 0x8000u) & 0xffff0000u);
          pk[1][ii] = ((__float_as_uint(p10) + 0x8000u) >> 16) |
                      ((__float_as_uint(p11) + 0x8000u) & 0xffff0000u);
        }
      }

      short8 pf[4];
#pragma unroll
      for (int ks2 = 0; ks2 < 4; ks2++) {
        int km = ks2 >> 1, h4 = (ks2 & 1) * 4;
        unsigned A0 = pk[km][h4 + 0], A1 = pk[km][h4 + 1];
        unsigned B0 = pk[km][h4 + 2], B1 = pk[km][h4 + 3];
        unsigned tA0 = (unsigned)__shfl_xor((int)A0, 32);
        unsigned tA1 = (unsigned)__shfl_xor((int)A1, 32);
        unsigned tB0 = (unsigned)__shfl_xor((int)B0, 32);
        unsigned tB1 = (unsigned)__shfl_xor((int)B1, 32);
        union { unsigned u[4]; short8 sh; } fr;
        fr.u[0] = hi ? tB0 : A0;
        fr.u[1] = hi ? tB1 : A1;
        fr.u[2] = hi ? B0 : tA0;
        fr.u[3] = hi ? B1 : tA1;
        pf[ks2] = fr.sh;
      }

#pragma unroll
      for (int am = 0; am < 2; am++)
#pragma unroll
        for (int ks2 = 0; ks2 < 4; ks2++)
          o[am] = __builtin_amdgcn_mfma_f32_32x32x16_bf16(vv[am * 4 + ks2], pf[ks2], o[am], 0, 0, 0);
    }

    float l_tot = l_run + __shfl_xor(l_run, 32);
    float inv = 1.0f / l_tot;
    size_t obase = (size_t)(rowbase + q_lane) * 1024 + h * 64;
#pragma unroll
    for (int am = 0; am < 2; am++)
#pragma unroll
      for (int k = 0; k < 4; k++) {
        ushort4 w;
        w.x = f2bf(o[am][4 * k + 0] * inv);
        w.y = f2bf(o[am][4 * k + 1] * inv);
        w.z = f2bf(o[am][4 * k + 2] * inv);
        w.w = f2bf(o[am][4 * k + 3] * inv);
        *(ushort4*)&ctx[obase + am * 32 + k * 8 + hi4] = w;
      }
  }
}

// ---------------- launch ----------------
extern "C" void kernel_launch(void* const* d_in, const int* in_sizes, int n_in,
                              void* d_out, int out_size, void* d_ws, size_t ws_size,
                              hipStream_t stream) {
  const float* x      = (const float*)d_in[0];
  const float* w_qkv  = (const float*)d_in[1];
  const float* w_proj = (const float*)d_in[2];
  float* out = (float*)d_out;

  char* ws = (char*)d_ws;
  const size_t MB = 1024 * 1024;
  u16* qbuf   = (u16*)(ws);
  u16* kbuf   = (u16*)(ws + 16 * MB);
  u16* vbuf   = (u16*)(ws + 32 * MB);
  u16* xb     = (u16*)(ws + 48 * MB);
  u16* kpack  = (u16*)(ws + 48 * MB);  // overwrites xb after gemm1
  u16* vpack  = (u16*)(ws + 64 * MB);
  u16* wqkvT  = (u16*)(ws + 80 * MB);
  u16* wprojT = (u16*)(ws + 86 * MB);
  u16* ctx    = kbuf;                  // overwrites kbuf after pack

  cast_kernel<<<8192, 256, 0, stream>>>(x, xb, 2097152);
  tcast_kernel<<<dim3(96, 32), 256, 0, stream>>>(w_qkv, wqkvT, 1024, 3072);
  tcast_kernel<<<dim3(32, 32), 256, 0, stream>>>(w_proj, wprojT, 1024, 1024);

  gemm_qkv<<<dim3(384), 512, 0, stream>>>(xb, wqkvT, qbuf, kbuf, vbuf);
  pack_kv<<<dim3(32, 16, 4), 256, 0, stream>>>(kbuf, vbuf, kpack, vpack);
  attn_kernel<<<dim3(64, 8), 256, 0, stream>>>(qbuf, kpack, vpack, ctx);
  gemm_proj<<<dim3(8, 64), 256, 0, stream>>>(ctx, wprojT, out);
}

// Round 4
// 252.488 us; speedup vs baseline: 1.0226x; 1.0077x over previous
//
#include <hip/hip_runtime.h>
#include <hip/hip_bf16.h>

typedef unsigned short u16;
typedef __attribute__((ext_vector_type(8))) short short8;
typedef __attribute__((ext_vector_type(4))) float f32x4;
typedef __attribute__((ext_vector_type(16))) float f32x16;

__device__ inline u16 f2bf(float f) {
  unsigned u = __float_as_uint(f);
  u += 0x7fffu + ((u >> 16) & 1u);   // round-to-nearest-even
  return (u16)(u >> 16);
}

// ---------------- cast fp32 -> bf16 (vectorized x4) ----------------
__global__ __launch_bounds__(256) void cast_kernel(const float* __restrict__ in,
                                                   u16* __restrict__ out, int n4) {
  int i = blockIdx.x * 256 + threadIdx.x;
  if (i >= n4) return;
  float4 v = ((const float4*)in)[i];
  ushort4 o;
  o.x = f2bf(v.x); o.y = f2bf(v.y); o.z = f2bf(v.z); o.w = f2bf(v.w);
  ((ushort4*)out)[i] = o;
}

// ---------------- transpose-cast: fp32 [K][N] -> bf16 [N][K] ----------------
__global__ __launch_bounds__(256) void tcast_kernel(const float* __restrict__ in,
                                                    u16* __restrict__ out, int K, int N) {
  __shared__ float tile[32][33];
  int bx = blockIdx.x * 32;  // N offset
  int by = blockIdx.y * 32;  // K offset
  int tx = threadIdx.x & 31, ty = threadIdx.x >> 5;
#pragma unroll
  for (int i = 0; i < 4; i++) {
    int r = ty + i * 8;
    tile[r][tx] = in[(size_t)(by + r) * N + bx + tx];
  }
  __syncthreads();
#pragma unroll
  for (int i = 0; i < 4; i++) {
    int r = ty + i * 8;
    out[(size_t)(bx + r) * K + by + tx] = f2bf(tile[tx][r]);
  }
}

// ---------------- pack K,V into fragment-major layout ----------------
__global__ __launch_bounds__(256) void pack_kv(const u16* __restrict__ kbuf,
                                               const u16* __restrict__ vbuf,
                                               u16* __restrict__ kpack,
                                               u16* __restrict__ vpack) {
  __shared__ __align__(16) u16 ktile[64 * 72];
  __shared__ __align__(16) u16 vtile[64 * 72];
  int t = threadIdx.x;
  int kt = blockIdx.x, h = blockIdx.y, b = blockIdx.z;
  int bh = b * 16 + h;
  size_t rb = (size_t)(b * 2048 + kt * 64);
#pragma unroll
  for (int i = 0; i < 2; i++) {
    int idx = i * 256 + t; int r = idx >> 3, c8 = (idx & 7) * 8;
    *(uint4*)&ktile[r * 72 + c8] = *(const uint4*)(kbuf + (rb + r) * 1024 + h * 64 + c8);
    *(uint4*)&vtile[r * 72 + c8] = *(const uint4*)(vbuf + (rb + r) * 1024 + h * 64 + c8);
  }
  __syncthreads();
  u16* kd = kpack + ((size_t)bh * 32 + kt) * 4096;
  u16* vd = vpack + ((size_t)bh * 32 + kt) * 4096;
#pragma unroll
  for (int i = 0; i < 2; i++) {
    int idx = i * 256 + t;
    int j = idx >> 6, lane = idx & 63, l31 = lane & 31, hi5 = lane >> 5;
    *(uint4*)(kd + j * 512 + lane * 8) =
        *(const uint4*)&ktile[((j >> 2) * 32 + l31) * 72 + (j & 3) * 16 + hi5 * 8];
    union { u16 s[8]; uint4 u; } pv;
#pragma unroll
    for (int e = 0; e < 8; e++)
      pv.s[e] = vtile[((j & 3) * 16 + hi5 * 8 + e) * 72 + (j >> 2) * 32 + l31];
    *(uint4*)(vd + j * 512 + lane * 8) = pv.u;
  }
}

// ==================== gemm_qkv: 256x256, BK=64, m201-faithful 8-phase ==============
// Identical to round 3 EXCEPT: LGKM0 no longer carries sched_barrier(0).
// The sched_barrier at every phase boundary was pinning the LLVM scheduler,
// forbidding cross-phase pipelining (documented regression mode: m141, -43%).
// Correctness unchanged: MFMA<-ds_read deps are compiler-tracked; LDS buffer WAR
// is covered by barriers + counted vmcnt; "memory" clobbers pin the LDS loads.

#define VMWAIT(n) asm volatile("s_waitcnt vmcnt(" #n ")" ::: "memory")
#define LGKM0() asm volatile("s_waitcnt lgkmcnt(0)" ::: "memory")
#define BAR() asm volatile("s_barrier" ::: "memory")

__device__ __forceinline__ void gll16(const u16* g, u16* l) {
  __builtin_amdgcn_global_load_lds((const __attribute__((address_space(1))) unsigned*)g,
                                   (__attribute__((address_space(3))) unsigned*)l, 16, 0, 0);
}

__global__ __launch_bounds__(512, 2) void gemm_qkv(const u16* __restrict__ A,
                                                   const u16* __restrict__ Bt,
                                                   u16* __restrict__ qb,
                                                   u16* __restrict__ kb,
                                                   u16* __restrict__ vb) {
  __shared__ u16 lds[65536];  // 128 KB: buffer b at b*32768 u16
  int tid = threadIdx.x;
  int w = tid >> 6, lane = tid & 63, l15 = lane & 15, quad = lane >> 4;
  int wr = w >> 2, wc = w & 3;

  // bijective XCD swizzle (384 % 8 == 0)
  int bid = blockIdx.x;
  int wgid = (bid & 7) * 48 + (bid >> 3);
  int bm = (wgid / 12) * 256;
  int bn3 = (wgid % 12) * 256;

  // ---- staging addresses: per gload, wave w covers 16 rows x 32 k of one k-sub ----
  int srow = lane >> 2;                              // row within 16-row subtile
  int kswz = ((lane & 3) * 8) ^ ((lane >> 5) << 4);  // inverse-swizzled source k (u16)
  const u16* gA0 = A + (size_t)(bm + w * 16 + srow) * 1024 + kswz;
  const u16* gA1 = A + (size_t)(bm + 128 + w * 16 + srow) * 1024 + kswz;
  const u16* gB0 = Bt + (size_t)(bn3 + w * 16 + srow) * 1024 + kswz;
  const u16* gB1 = Bt + (size_t)(bn3 + 128 + w * 16 + srow) * 1024 + kswz;

  // ---- fragment read offsets (u16 units, swizzled); + m*512 / n*512, + s*4096 ----
  int kq = (quad * 8) ^ ((l15 & 8) << 1);
  int aoff = wr * 8192 + l15 * 32 + kq;                         // within A-half pair
  int boff = 16384 + (wc >> 1) * 8192 + (wc & 1) * 2048 + l15 * 32 + kq;

  f32x4 acc[8][4];
#pragma unroll
  for (int m = 0; m < 8; m++)
#pragma unroll
    for (int n = 0; n < 4; n++) acc[m][n] = (f32x4)0.0f;

  short8 a[8], bA[4], bB[4];

#define STAGE_AH0(T)                                          \
  do {                                                        \
    u16* d_ = lds + ((T) & 1) * 32768 + w * 512;              \
    gll16(gA0 + (size_t)(T) * 64, d_);                        \
    gll16(gA0 + (size_t)(T) * 64 + 32, d_ + 4096);            \
  } while (0)
#define STAGE_AH1(T)                                          \
  do {                                                        \
    u16* d_ = lds + ((T) & 1) * 32768 + 8192 + w * 512;       \
    gll16(gA1 + (size_t)(T) * 64, d_);                        \
    gll16(gA1 + (size_t)(T) * 64 + 32, d_ + 4096);            \
  } while (0)
#define STAGE_BH0(T)                                          \
  do {                                                        \
    u16* d_ = lds + ((T) & 1) * 32768 + 16384 + w * 512;      \
    gll16(gB0 + (size_t)(T) * 64, d_);                        \
    gll16(gB0 + (size_t)(T) * 64 + 32, d_ + 4096);            \
  } while (0)
#define STAGE_BH1(T)                                          \
  do {                                                        \
    u16* d_ = lds + ((T) & 1) * 32768 + 24576 + w * 512;      \
    gll16(gB1 + (size_t)(T) * 64, d_);                        \
    gll16(gB1 + (size_t)(T) * 64 + 32, d_ + 4096);            \
  } while (0)

#define MFMA16(NLO, BV0, BV1)                                                                  \
  do {                                                                                         \
    __builtin_amdgcn_s_setprio(1);                                                             \
    _Pragma("unroll") for (int m = 0; m < 8; m++)                                              \
        acc[m][NLO] = __builtin_amdgcn_mfma_f32_16x16x32_bf16(a[m], BV0, acc[m][NLO], 0, 0, 0);\
    _Pragma("unroll") for (int m = 0; m < 8; m++)                                              \
        acc[m][NLO + 1] =                                                                      \
            __builtin_amdgcn_mfma_f32_16x16x32_bf16(a[m], BV1, acc[m][NLO + 1], 0, 0, 0);      \
    __builtin_amdgcn_s_setprio(0);                                                             \
  } while (0)

#define PHASE1(T, DOSTG)                                                                       \
  do {                                                                                         \
    const u16* bc_ = lds + ((T) & 1) * 32768;                                                  \
    _Pragma("unroll") for (int m = 0; m < 8; m++)                                              \
        a[m] = *(const short8*)(bc_ + aoff + m * 512);                                         \
    if (DOSTG) STAGE_AH0((T) + 1);                                                             \
    BAR(); LGKM0();                                                                            \
    MFMA16(0, bA[0], bA[1]);                                                                   \
    BAR();                                                                                     \
  } while (0)

#define PHASE2(T, DOSTG)                                                                       \
  do {                                                                                         \
    const u16* bc_ = lds + ((T) & 1) * 32768;                                                  \
    _Pragma("unroll") for (int n = 0; n < 4; n++)                                              \
        bB[n] = *(const short8*)(bc_ + boff + 4096 + n * 512);                                 \
    if (DOSTG) STAGE_AH1((T) + 1);                                                             \
    BAR(); LGKM0();                                                                            \
    MFMA16(2, bA[2], bA[3]);                                                                   \
    BAR();                                                                                     \
  } while (0)

#define PHASE3(T, DOSTG, VMN)                                                                  \
  do {                                                                                         \
    const u16* bc_ = lds + ((T) & 1) * 32768;                                                  \
    _Pragma("unroll") for (int m = 0; m < 8; m++)                                              \
        a[m] = *(const short8*)(bc_ + aoff + 4096 + m * 512);                                  \
    if (DOSTG) STAGE_BH0((T) + 2);                                                             \
    BAR(); LGKM0();                                                                            \
    MFMA16(0, bB[0], bB[1]);                                                                   \
    VMN;                                                                                       \
    BAR();                                                                                     \
  } while (0)

#define PHASE4(T, DORD, DOSTG, VMN)                                                            \
  do {                                                                                         \
    if (DORD) {                                                                                \
      const u16* bn_ = lds + (((T) + 1) & 1) * 32768;                                          \
      _Pragma("unroll") for (int n = 0; n < 4; n++)                                            \
          bA[n] = *(const short8*)(bn_ + boff + n * 512);                                      \
    }                                                                                          \
    if (DOSTG) STAGE_BH1((T) + 2);                                                             \
    BAR(); LGKM0();                                                                            \
    MFMA16(2, bB[2], bB[3]);                                                                   \
    VMN;                                                                                       \
    BAR();                                                                                     \
  } while (0)

  // ---- prologue: B(0), A(0), B(1); retire B(0)+A(0); pre-read bA = b@s0(0) ----
  STAGE_BH0(0); STAGE_BH1(0); STAGE_AH0(0); STAGE_AH1(0); STAGE_BH0(1); STAGE_BH1(1);
  VMWAIT(4);  // 12 issued; keep B(1)'s 4 in flight
  BAR();
  {
    const u16* bc_ = lds;  // buffer 0
#pragma unroll
    for (int n = 0; n < 4; n++) bA[n] = *(const short8*)(bc_ + boff + n * 512);
  }

  // ---- main loop: K-tiles 0..13 uniform ----
  for (int T = 0; T < 14; ++T) {
    PHASE1(T, 1);
    PHASE2(T, 1);
    PHASE3(T, 1, VMWAIT(6));
    PHASE4(T, 1, 1, VMWAIT(4));
  }
  // ---- tail: T=14 (B-stage off), T=15 (all off, drained) ----
  PHASE1(14, 1);
  PHASE2(14, 1);
  PHASE3(14, 0, VMWAIT(4));   // retire B(15); keep A(15)
  PHASE4(14, 1, 0, VMWAIT(0));  // retire A(15)
  PHASE1(15, 0);
  PHASE2(15, 0);
  PHASE3(15, 0, (void)0);
  PHASE4(15, 0, 0, (void)0);

#undef PHASE1
#undef PHASE2
#undef PHASE3
#undef PHASE4
#undef MFMA16
#undef STAGE_AH0
#undef STAGE_AH1
#undef STAGE_BH0
#undef STAGE_BH1

  // ---- epilogue: q/k/v split; Q pre-scaled by (1/8)*log2(e) for exp2-domain attn ----
  u16* dst = (bn3 < 1024) ? qb : (bn3 < 2048) ? kb : vb;
  float scl = (bn3 < 1024) ? 0.18033688011112f : 1.0f;
  int bnl = bn3 & 1023;
  int rbase = bm + wr * 128 + quad * 4;
  int cbase = bnl + wc * 64 + l15;
#pragma unroll
  for (int m = 0; m < 8; m++)
#pragma unroll
    for (int n = 0; n < 4; n++)
#pragma unroll
      for (int r = 0; r < 4; r++)
        dst[(size_t)(rbase + m * 16 + r) * 1024 + cbase + n * 16] = f2bf(acc[m][n][r] * scl);
}

// ---------------- proj GEMM (m97-style 128x128, unchanged this round) ----------------
#define GEMM_BODY(KSTR)                                                                       \
  __shared__ __align__(16) u16 As[128 * 32];                                                  \
  __shared__ __align__(16) u16 Bs[128 * 32];                                                  \
  int t = threadIdx.x;                                                                        \
  int wave = t >> 6, lane = t & 63, l15 = lane & 15, quad = lane >> 4;                        \
  int bn = blockIdx.x * 128, bm = blockIdx.y * 128;                                           \
  int wm = (wave >> 1) * 64, wn = (wave & 1) * 64;                                            \
  f32x4 acc[4][4];                                                                            \
  for (int i = 0; i < 4; i++)                                                                 \
    for (int j = 0; j < 4; j++) acc[i][j] = (f32x4)0.0f;                                      \
  int srow = wave * 16 + (lane >> 2);                                                         \
  int scol = (lane & 3) * 8;                                                                  \
  const u16* ga0 = A + (size_t)(bm + srow) * KSTR + scol;                                     \
  const u16* ga1 = A + (size_t)(bm + 64 + srow) * KSTR + scol;                                \
  const u16* gb0 = Bt + (size_t)(bn + srow) * KSTR + scol;                                    \
  const u16* gb1 = Bt + (size_t)(bn + 64 + srow) * KSTR + scol;                               \
  u16* lA0 = As + wave * 512;                                                                 \
  u16* lA1 = As + 2048 + wave * 512;                                                          \
  u16* lB0 = Bs + wave * 512;                                                                 \
  u16* lB1 = Bs + 2048 + wave * 512;                                                          \
  for (int k0 = 0; k0 < KSTR; k0 += 32) {                                                     \
    __syncthreads();                                                                          \
    __builtin_amdgcn_global_load_lds((const __attribute__((address_space(1))) unsigned*)(ga0 + k0), \
                                     (__attribute__((address_space(3))) unsigned*)lA0, 16, 0, 0);   \
    __builtin_amdgcn_global_load_lds((const __attribute__((address_space(1))) unsigned*)(ga1 + k0), \
                                     (__attribute__((address_space(3))) unsigned*)lA1, 16, 0, 0);   \
    __builtin_amdgcn_global_load_lds((const __attribute__((address_space(1))) unsigned*)(gb0 + k0), \
                                     (__attribute__((address_space(3))) unsigned*)lB0, 16, 0, 0);   \
    __builtin_amdgcn_global_load_lds((const __attribute__((address_space(1))) unsigned*)(gb1 + k0), \
                                     (__attribute__((address_space(3))) unsigned*)lB1, 16, 0, 0);   \
    __syncthreads();                                                                          \
    short8 a[4], b[4];                                                                        \
    for (int mt = 0; mt < 4; mt++)                                                            \
      a[mt] = *(const short8*)(&As[(wm + mt * 16 + l15) * 32 + quad * 8]);                    \
    for (int nt = 0; nt < 4; nt++)                                                            \
      b[nt] = *(const short8*)(&Bs[(wn + nt * 16 + l15) * 32 + quad * 8]);                    \
    for (int mt = 0; mt < 4; mt++)                                                            \
      for (int nt = 0; nt < 4; nt++)                                                          \
        acc[mt][nt] = __builtin_amdgcn_mfma_f32_16x16x32_bf16(a[mt], b[nt], acc[mt][nt], 0, 0, 0); \
  }

__global__ __launch_bounds__(256) void gemm_proj(const u16* __restrict__ A,
                                                 const u16* __restrict__ Bt,
                                                 float* __restrict__ Co) {
  GEMM_BODY(1024)
#pragma unroll
  for (int mt = 0; mt < 4; mt++)
#pragma unroll
    for (int nt = 0; nt < 4; nt++)
#pragma unroll
      for (int r = 0; r < 4; r++) {
        int row = bm + wm + mt * 16 + quad * 4 + r;
        int col = bn + wn + nt * 16 + l15;
        Co[(size_t)row * 1024 + col] = acc[mt][nt][r];
      }
}

// ---------------- flash attention (unchanged) ----------------
__global__ __launch_bounds__(256, 2) void attn_kernel(const u16* __restrict__ qbuf,
                                                      const u16* __restrict__ kpack,
                                                      const u16* __restrict__ vpack,
                                                      u16* __restrict__ ctx) {
  int t = threadIdx.x;
  int wave = t >> 6, lane = t & 63, l31 = lane & 31, hi = lane >> 5;
  int bh = blockIdx.x;
  int s = (int)blockIdx.y * 4 + wave;
  int b = bh >> 4, h = bh & 15;
  int rowbase = b * 2048;
  int hi4 = hi * 4;

  const u16* kp = kpack + (size_t)bh * (32 * 4096) + lane * 8;
  const u16* vp = vpack + (size_t)bh * (32 * 4096) + lane * 8;

#pragma unroll
  for (int ph = 0; ph < 2; ph++) {
    int strip = ph ? 63 - s : s;
    int q0 = strip * 32;
    int q_lane = q0 + l31;

    const u16* qp = qbuf + (size_t)(rowbase + q_lane) * 1024 + h * 64 + hi * 8;
    short8 qf[4];
#pragma unroll
    for (int ks = 0; ks < 4; ks++) qf[ks] = *(const short8*)(qp + ks * 16);

    float l_run = 0.0f;
    f32x16 o[2];
    o[0] = (f32x16)0.0f; o[1] = (f32x16)0.0f;
    int ktmax = (q0 + 31) >> 6;

    for (int kt = 0; kt <= ktmax; kt++) {
      const u16* kb = kp + kt * 4096;
      const u16* vb = vp + kt * 4096;

      short8 ka[8], vv[8];
#pragma unroll
      for (int j = 0; j < 8; j++) {
        ka[j] = *(const short8*)(kb + j * 512);
        vv[j] = *(const short8*)(vb + j * 512);
      }

      f32x16 st0 = (f32x16)0.0f, st1 = (f32x16)0.0f;
#pragma unroll
      for (int ks = 0; ks < 4; ks++) {
        st0 = __builtin_amdgcn_mfma_f32_32x32x16_bf16(ka[ks], qf[ks], st0, 0, 0, 0);
        st1 = __builtin_amdgcn_mfma_f32_32x32x16_bf16(ka[4 + ks], qf[ks], st1, 0, 0, 0);
      }

      unsigned pk[2][8];
      if (kt == ktmax) {
#pragma unroll
        for (int ii = 0; ii < 8; ii++) {
          int key = kt * 64 + ((2 * ii) & 3) + 8 * ((2 * ii) >> 2) + hi4;
          float p00 = (key     <= q_lane) ? __builtin_amdgcn_exp2f(st0[2 * ii])     : 0.0f;
          float p01 = (key + 1 <= q_lane) ? __builtin_amdgcn_exp2f(st0[2 * ii + 1]) : 0.0f;
          float p10 = (key + 32 <= q_lane) ? __builtin_amdgcn_exp2f(st1[2 * ii])     : 0.0f;
          float p11 = (key + 33 <= q_lane) ? __builtin_amdgcn_exp2f(st1[2 * ii + 1]) : 0.0f;
          l_run += p00 + p01 + p10 + p11;
          pk[0][ii] = ((__float_as_uint(p00) + 0x8000u) >> 16) |
                      ((__float_as_uint(p01) + 0x8000u) & 0xffff0000u);
          pk[1][ii] = ((__float_as_uint(p10) + 0x8000u) >> 16) |
                      ((__float_as_uint(p11) + 0x8000u) & 0xffff0000u);
        }
      } else {
#pragma unroll
        for (int ii = 0; ii < 8; ii++) {
          float p00 = __builtin_amdgcn_exp2f(st0[2 * ii]);
          float p01 = __builtin_amdgcn_exp2f(st0[2 * ii + 1]);
          float p10 = __builtin_amdgcn_exp2f(st1[2 * ii]);
          float p11 = __builtin_amdgcn_exp2f(st1[2 * ii + 1]);
          l_run += p00 + p01 + p10 + p11;
          pk[0][ii] = ((__float_as_uint(p00) + 0x8000u) >> 16) |
                      ((__float_as_uint(p01) + 0x8000u) & 0xffff0000u);
          pk[1][ii] = ((__float_as_uint(p10) + 0x8000u) >> 16) |
                      ((__float_as_uint(p11) + 0x8000u) & 0xffff0000u);
        }
      }

      short8 pf[4];
#pragma unroll
      for (int ks2 = 0; ks2 < 4; ks2++) {
        int km = ks2 >> 1, h4 = (ks2 & 1) * 4;
        unsigned A0 = pk[km][h4 + 0], A1 = pk[km][h4 + 1];
        unsigned B0 = pk[km][h4 + 2], B1 = pk[km][h4 + 3];
        unsigned tA0 = (unsigned)__shfl_xor((int)A0, 32);
        unsigned tA1 = (unsigned)__shfl_xor((int)A1, 32);
        unsigned tB0 = (unsigned)__shfl_xor((int)B0, 32);
        unsigned tB1 = (unsigned)__shfl_xor((int)B1, 32);
        union { unsigned u[4]; short8 sh; } fr;
        fr.u[0] = hi ? tB0 : A0;
        fr.u[1] = hi ? tB1 : A1;
        fr.u[2] = hi ? B0 : tA0;
        fr.u[3] = hi ? B1 : tA1;
        pf[ks2] = fr.sh;
      }

#pragma unroll
      for (int am = 0; am < 2; am++)
#pragma unroll
        for (int ks2 = 0; ks2 < 4; ks2++)
          o[am] = __builtin_amdgcn_mfma_f32_32x32x16_bf16(vv[am * 4 + ks2], pf[ks2], o[am], 0, 0, 0);
    }

    float l_tot = l_run + __shfl_xor(l_run, 32);
    float inv = 1.0f / l_tot;
    size_t obase = (size_t)(rowbase + q_lane) * 1024 + h * 64;
#pragma unroll
    for (int am = 0; am < 2; am++)
#pragma unroll
      for (int k = 0; k < 4; k++) {
        ushort4 w;
        w.x = f2bf(o[am][4 * k + 0] * inv);
        w.y = f2bf(o[am][4 * k + 1] * inv);
        w.z = f2bf(o[am][4 * k + 2] * inv);
        w.w = f2bf(o[am][4 * k + 3] * inv);
        *(ushort4*)&ctx[obase + am * 32 + k * 8 + hi4] = w;
      }
  }
}

// ---------------- launch ----------------
extern "C" void kernel_launch(void* const* d_in, const int* in_sizes, int n_in,
                              void* d_out, int out_size, void* d_ws, size_t ws_size,
                              hipStream_t stream) {
  const float* x      = (const float*)d_in[0];
  const float* w_qkv  = (const float*)d_in[1];
  const float* w_proj = (const float*)d_in[2];
  float* out = (float*)d_out;

  char* ws = (char*)d_ws;
  const size_t MB = 1024 * 1024;
  u16* qbuf   = (u16*)(ws);
  u16* kbuf   = (u16*)(ws + 16 * MB);
  u16* vbuf   = (u16*)(ws + 32 * MB);
  u16* xb     = (u16*)(ws + 48 * MB);
  u16* kpack  = (u16*)(ws + 48 * MB);  // overwrites xb after gemm1
  u16* vpack  = (u16*)(ws + 64 * MB);
  u16* wqkvT  = (u16*)(ws + 80 * MB);
  u16* wprojT = (u16*)(ws + 86 * MB);
  u16* ctx    = kbuf;                  // overwrites kbuf after pack

  cast_kernel<<<8192, 256, 0, stream>>>(x, xb, 2097152);
  tcast_kernel<<<dim3(96, 32), 256, 0, stream>>>(w_qkv, wqkvT, 1024, 3072);
  tcast_kernel<<<dim3(32, 32), 256, 0, stream>>>(w_proj, wprojT, 1024, 1024);

  gemm_qkv<<<dim3(384), 512, 0, stream>>>(xb, wqkvT, qbuf, kbuf, vbuf);
  pack_kv<<<dim3(32, 16, 4), 256, 0, stream>>>(kbuf, vbuf, kpack, vpack);
  attn_kernel<<<dim3(64, 8), 256, 0, stream>>>(qbuf, kpack, vpack, ctx);
  gemm_proj<<<dim3(8, 64), 256, 0, stream>>>(ctx, wprojT, out);
}

// Round 5
// 242.766 us; speedup vs baseline: 1.0636x; 1.0400x over previous
//
#include <hip/hip_runtime.h>
#include <hip/hip_bf16.h>

typedef unsigned short u16;
typedef __attribute__((ext_vector_type(8))) short short8;
typedef __attribute__((ext_vector_type(4))) float f32x4;
typedef __attribute__((ext_vector_type(16))) float f32x16;

__device__ inline u16 f2bf(float f) {
  unsigned u = __float_as_uint(f);
  u += 0x7fffu + ((u >> 16) & 1u);   // round-to-nearest-even
  return (u16)(u >> 16);
}

// ---------------- cast fp32 -> bf16 (vectorized x4) ----------------
__global__ __launch_bounds__(256) void cast_kernel(const float* __restrict__ in,
                                                   u16* __restrict__ out, int n4) {
  int i = blockIdx.x * 256 + threadIdx.x;
  if (i >= n4) return;
  float4 v = ((const float4*)in)[i];
  ushort4 o;
  o.x = f2bf(v.x); o.y = f2bf(v.y); o.z = f2bf(v.z); o.w = f2bf(v.w);
  ((ushort4*)out)[i] = o;
}

// ---------------- transpose-cast: fp32 [K][N] -> bf16 [N][K] ----------------
__global__ __launch_bounds__(256) void tcast_kernel(const float* __restrict__ in,
                                                    u16* __restrict__ out, int K, int N) {
  __shared__ float tile[32][33];
  int bx = blockIdx.x * 32;  // N offset
  int by = blockIdx.y * 32;  // K offset
  int tx = threadIdx.x & 31, ty = threadIdx.x >> 5;
#pragma unroll
  for (int i = 0; i < 4; i++) {
    int r = ty + i * 8;
    tile[r][tx] = in[(size_t)(by + r) * N + bx + tx];
  }
  __syncthreads();
#pragma unroll
  for (int i = 0; i < 4; i++) {
    int r = ty + i * 8;
    out[(size_t)(bx + r) * K + by + tx] = f2bf(tile[tx][r]);
  }
}

// ==================== gemm_qkv: 256x256, BK=64, 4-phase, FUSED PACK EPILOGUE =======
// Compute core identical to round 4 (all schedule variants measured equal).
// NEW: K- and V-third blocks write the attention fragment-major pack layout
// DIRECTLY from the accumulator (pack_kv kernel deleted; kbuf/vbuf round-trip
// eliminated, ~67 MB HBM traffic + 1 launch saved).
// Pack layout (per (bh, kt64), 16 frags x 1KB; frag j, lane l, elem e):
//   K: element (kr,d):  j=(kr>>5)*4+(d>>4)  lane=(kr&31)+((d>>3)&1)*32  e=d&7
//   V: element (s64,d): j=(d>>5)*4+(s64>>4) lane=(d&31)+((s64>>3)&1)*32 e=s64&7
// Verified bijective vs attn_kernel's reads (ka/vv[j] at j*512+lane*8).

#define VMWAIT(n) asm volatile("s_waitcnt vmcnt(" #n ")" ::: "memory")
#define LGKM0() asm volatile("s_waitcnt lgkmcnt(0)" ::: "memory")
#define BAR() asm volatile("s_barrier" ::: "memory")

__device__ __forceinline__ void gll16(const u16* g, u16* l) {
  __builtin_amdgcn_global_load_lds((const __attribute__((address_space(1))) unsigned*)g,
                                   (__attribute__((address_space(3))) unsigned*)l, 16, 0, 0);
}

__global__ __launch_bounds__(512, 2) void gemm_qkv(const u16* __restrict__ A,
                                                   const u16* __restrict__ Bt,
                                                   u16* __restrict__ qb,
                                                   u16* __restrict__ kpack,
                                                   u16* __restrict__ vpack) {
  __shared__ u16 lds[65536];  // 128 KB: buffer b at b*32768 u16
  int tid = threadIdx.x;
  int w = tid >> 6, lane = tid & 63, l15 = lane & 15, quad = lane >> 4;
  int wr = w >> 2, wc = w & 3;

  // bijective XCD swizzle (384 % 8 == 0)
  int bid = blockIdx.x;
  int wgid = (bid & 7) * 48 + (bid >> 3);
  int bm = (wgid / 12) * 256;
  int bn3 = (wgid % 12) * 256;

  // ---- staging addresses: per gload, wave w covers 16 rows x 32 k of one k-sub ----
  int srow = lane >> 2;                              // row within 16-row subtile
  int kswz = ((lane & 3) * 8) ^ ((lane >> 5) << 4);  // inverse-swizzled source k (u16)
  const u16* gA0 = A + (size_t)(bm + w * 16 + srow) * 1024 + kswz;
  const u16* gA1 = A + (size_t)(bm + 128 + w * 16 + srow) * 1024 + kswz;
  const u16* gB0 = Bt + (size_t)(bn3 + w * 16 + srow) * 1024 + kswz;
  const u16* gB1 = Bt + (size_t)(bn3 + 128 + w * 16 + srow) * 1024 + kswz;

  // ---- fragment read offsets (u16 units, swizzled); + m*512 / n*512, + s*4096 ----
  int kq = (quad * 8) ^ ((l15 & 8) << 1);
  int aoff = wr * 8192 + l15 * 32 + kq;                         // within A-half pair
  int boff = 16384 + (wc >> 1) * 8192 + (wc & 1) * 2048 + l15 * 32 + kq;

  f32x4 acc[8][4];
#pragma unroll
  for (int m = 0; m < 8; m++)
#pragma unroll
    for (int n = 0; n < 4; n++) acc[m][n] = (f32x4)0.0f;

  short8 a[8], bA[4], bB[4];

#define STAGE_AH0(T)                                          \
  do {                                                        \
    u16* d_ = lds + ((T) & 1) * 32768 + w * 512;              \
    gll16(gA0 + (size_t)(T) * 64, d_);                        \
    gll16(gA0 + (size_t)(T) * 64 + 32, d_ + 4096);            \
  } while (0)
#define STAGE_AH1(T)                                          \
  do {                                                        \
    u16* d_ = lds + ((T) & 1) * 32768 + 8192 + w * 512;       \
    gll16(gA1 + (size_t)(T) * 64, d_);                        \
    gll16(gA1 + (size_t)(T) * 64 + 32, d_ + 4096);            \
  } while (0)
#define STAGE_BH0(T)                                          \
  do {                                                        \
    u16* d_ = lds + ((T) & 1) * 32768 + 16384 + w * 512;      \
    gll16(gB0 + (size_t)(T) * 64, d_);                        \
    gll16(gB0 + (size_t)(T) * 64 + 32, d_ + 4096);            \
  } while (0)
#define STAGE_BH1(T)                                          \
  do {                                                        \
    u16* d_ = lds + ((T) & 1) * 32768 + 24576 + w * 512;      \
    gll16(gB1 + (size_t)(T) * 64, d_);                        \
    gll16(gB1 + (size_t)(T) * 64 + 32, d_ + 4096);            \
  } while (0)

#define MFMA16(NLO, BV0, BV1)                                                                  \
  do {                                                                                         \
    __builtin_amdgcn_s_setprio(1);                                                             \
    _Pragma("unroll") for (int m = 0; m < 8; m++)                                              \
        acc[m][NLO] = __builtin_amdgcn_mfma_f32_16x16x32_bf16(a[m], BV0, acc[m][NLO], 0, 0, 0);\
    _Pragma("unroll") for (int m = 0; m < 8; m++)                                              \
        acc[m][NLO + 1] =                                                                      \
            __builtin_amdgcn_mfma_f32_16x16x32_bf16(a[m], BV1, acc[m][NLO + 1], 0, 0, 0);      \
    __builtin_amdgcn_s_setprio(0);                                                             \
  } while (0)

#define PHASE1(T, DOSTG)                                                                       \
  do {                                                                                         \
    const u16* bc_ = lds + ((T) & 1) * 32768;                                                  \
    _Pragma("unroll") for (int m = 0; m < 8; m++)                                              \
        a[m] = *(const short8*)(bc_ + aoff + m * 512);                                         \
    if (DOSTG) STAGE_AH0((T) + 1);                                                             \
    BAR(); LGKM0();                                                                            \
    MFMA16(0, bA[0], bA[1]);                                                                   \
    BAR();                                                                                     \
  } while (0)

#define PHASE2(T, DOSTG)                                                                       \
  do {                                                                                         \
    const u16* bc_ = lds + ((T) & 1) * 32768;                                                  \
    _Pragma("unroll") for (int n = 0; n < 4; n++)                                              \
        bB[n] = *(const short8*)(bc_ + boff + 4096 + n * 512);                                 \
    if (DOSTG) STAGE_AH1((T) + 1);                                                             \
    BAR(); LGKM0();                                                                            \
    MFMA16(2, bA[2], bA[3]);                                                                   \
    BAR();                                                                                     \
  } while (0)

#define PHASE3(T, DOSTG, VMN)                                                                  \
  do {                                                                                         \
    const u16* bc_ = lds + ((T) & 1) * 32768;                                                  \
    _Pragma("unroll") for (int m = 0; m < 8; m++)                                              \
        a[m] = *(const short8*)(bc_ + aoff + 4096 + m * 512);                                  \
    if (DOSTG) STAGE_BH0((T) + 2);                                                             \
    BAR(); LGKM0();                                                                            \
    MFMA16(0, bB[0], bB[1]);                                                                   \
    VMN;                                                                                       \
    BAR();                                                                                     \
  } while (0)

#define PHASE4(T, DORD, DOSTG, VMN)                                                            \
  do {                                                                                         \
    if (DORD) {                                                                                \
      const u16* bn_ = lds + (((T) + 1) & 1) * 32768;                                          \
      _Pragma("unroll") for (int n = 0; n < 4; n++)                                            \
          bA[n] = *(const short8*)(bn_ + boff + n * 512);                                      \
    }                                                                                          \
    if (DOSTG) STAGE_BH1((T) + 2);                                                             \
    BAR(); LGKM0();                                                                            \
    MFMA16(2, bB[2], bB[3]);                                                                   \
    VMN;                                                                                       \
    BAR();                                                                                     \
  } while (0)

  // ---- prologue: B(0), A(0), B(1); retire B(0)+A(0); pre-read bA = b@s0(0) ----
  STAGE_BH0(0); STAGE_BH1(0); STAGE_AH0(0); STAGE_AH1(0); STAGE_BH0(1); STAGE_BH1(1);
  VMWAIT(4);  // 12 issued; keep B(1)'s 4 in flight
  BAR();
  {
    const u16* bc_ = lds;  // buffer 0
#pragma unroll
    for (int n = 0; n < 4; n++) bA[n] = *(const short8*)(bc_ + boff + n * 512);
  }

  // ---- main loop: K-tiles 0..13 uniform ----
  for (int T = 0; T < 14; ++T) {
    PHASE1(T, 1);
    PHASE2(T, 1);
    PHASE3(T, 1, VMWAIT(6));
    PHASE4(T, 1, 1, VMWAIT(4));
  }
  // ---- tail: T=14 (B-stage off), T=15 (all off, drained) ----
  PHASE1(14, 1);
  PHASE2(14, 1);
  PHASE3(14, 0, VMWAIT(4));   // retire B(15); keep A(15)
  PHASE4(14, 1, 0, VMWAIT(0));  // retire A(15)
  PHASE1(15, 0);
  PHASE2(15, 0);
  PHASE3(15, 0, (void)0);
  PHASE4(15, 0, 0, (void)0);

#undef PHASE1
#undef PHASE2
#undef PHASE3
#undef PHASE4
#undef MFMA16
#undef STAGE_AH0
#undef STAGE_AH1
#undef STAGE_BH0
#undef STAGE_BH1

  // ---- fused epilogue ----
  // Thread owns C[row][col]: row = bm + wr*128 + m*16 + quad*4 + r,
  //                          col(third-local) = bnl + wc*64 + n*16 + l15.
  if (bn3 < 1024) {
    // Q: row-major, pre-scaled by (1/8)*log2(e) for exp2-domain attention
    float scl = 0.18033688011112f;
    int rbase = bm + wr * 128 + quad * 4;
    int cbase = bn3 + wc * 64 + l15;
#pragma unroll
    for (int m = 0; m < 8; m++)
#pragma unroll
      for (int n = 0; n < 4; n++)
#pragma unroll
        for (int r = 0; r < 4; r++)
          qb[(size_t)(rbase + m * 16 + r) * 1024 + cbase + n * 16] = f2bf(acc[m][n][r] * scl);
  } else {
    int bnl = bn3 & 1023;
    int h = (bnl >> 6) + wc;             // head (wave covers exactly one head)
    int bh = (bm >> 11) * 16 + h;        // batch*16 + head
    int ktb = ((bm & 2047) >> 6) + wr * 2;  // kt base; + (m>>2)
    if (bn3 < 2048) {
      // K-pack: element (kr = (m&3)*16+quad*4+r, d = n*16+l15)
      int lhi = ((l15 >> 3) & 1) * 32;   // (d>>3)&1 (n*2 even)
      int e = l15 & 7;
#pragma unroll
      for (int m = 0; m < 8; m++) {
        u16* kd = kpack + ((size_t)bh * 32 + ktb + (m >> 2)) * 4096;
        int krb = (m & 3) * 16 + quad * 4;
        int jm = (krb >> 5) * 4;         // kr>=32 fixed within m (krb mult of 4, +r<4)
        int l31b = krb & 31;
#pragma unroll
        for (int n = 0; n < 4; n++)
#pragma unroll
          for (int r = 0; r < 4; r++) {
            int off = (jm + n) * 512 + (l31b + r + lhi) * 8 + e;
            kd[off] = f2bf(acc[m][n][r]);
          }
      }
    } else {
      // V-pack: element (s64 = (m&3)*16+quad*4+r, d = n*16+l15); r=0..3 are 4
      // consecutive u16 (e = (quad&1)*4 + r) -> ushort4 store.
      int e0 = (quad & 1) * 4;
      int hi5 = (quad >> 1) * 32;
#pragma unroll
      for (int m = 0; m < 8; m++) {
        u16* vd = vpack + ((size_t)bh * 32 + ktb + (m >> 2)) * 4096;
#pragma unroll
        for (int n = 0; n < 4; n++) {
          int off = ((n >> 1) * 4 + (m & 3)) * 512 +
                    ((n & 1) * 16 + l15 + hi5) * 8 + e0;
          ushort4 wv;
          wv.x = f2bf(acc[m][n][0]);
          wv.y = f2bf(acc[m][n][1]);
          wv.z = f2bf(acc[m][n][2]);
          wv.w = f2bf(acc[m][n][3]);
          *(ushort4*)(vd + off) = wv;
        }
      }
    }
  }
}

// ---------------- proj GEMM (m97-style 128x128, unchanged) ----------------
#define GEMM_BODY(KSTR)                                                                       \
  __shared__ __align__(16) u16 As[128 * 32];                                                  \
  __shared__ __align__(16) u16 Bs[128 * 32];                                                  \
  int t = threadIdx.x;                                                                        \
  int wave = t >> 6, lane = t & 63, l15 = lane & 15, quad = lane >> 4;                        \
  int bn = blockIdx.x * 128, bm = blockIdx.y * 128;                                           \
  int wm = (wave >> 1) * 64, wn = (wave & 1) * 64;                                            \
  f32x4 acc[4][4];                                                                            \
  for (int i = 0; i < 4; i++)                                                                 \
    for (int j = 0; j < 4; j++) acc[i][j] = (f32x4)0.0f;                                      \
  int srow = wave * 16 + (lane >> 2);                                                         \
  int scol = (lane & 3) * 8;                                                                  \
  const u16* ga0 = A + (size_t)(bm + srow) * KSTR + scol;                                     \
  const u16* ga1 = A + (size_t)(bm + 64 + srow) * KSTR + scol;                                \
  const u16* gb0 = Bt + (size_t)(bn + srow) * KSTR + scol;                                    \
  const u16* gb1 = Bt + (size_t)(bn + 64 + srow) * KSTR + scol;                               \
  u16* lA0 = As + wave * 512;                                                                 \
  u16* lA1 = As + 2048 + wave * 512;                                                          \
  u16* lB0 = Bs + wave * 512;                                                                 \
  u16* lB1 = Bs + 2048 + wave * 512;                                                          \
  for (int k0 = 0; k0 < KSTR; k0 += 32) {                                                     \
    __syncthreads();                                                                          \
    __builtin_amdgcn_global_load_lds((const __attribute__((address_space(1))) unsigned*)(ga0 + k0), \
                                     (__attribute__((address_space(3))) unsigned*)lA0, 16, 0, 0);   \
    __builtin_amdgcn_global_load_lds((const __attribute__((address_space(1))) unsigned*)(ga1 + k0), \
                                     (__attribute__((address_space(3))) unsigned*)lA1, 16, 0, 0);   \
    __builtin_amdgcn_global_load_lds((const __attribute__((address_space(1))) unsigned*)(gb0 + k0), \
                                     (__attribute__((address_space(3))) unsigned*)lB0, 16, 0, 0);   \
    __builtin_amdgcn_global_load_lds((const __attribute__((address_space(1))) unsigned*)(gb1 + k0), \
                                     (__attribute__((address_space(3))) unsigned*)lB1, 16, 0, 0);   \
    __syncthreads();                                                                          \
    short8 a[4], b[4];                                                                        \
    for (int mt = 0; mt < 4; mt++)                                                            \
      a[mt] = *(const short8*)(&As[(wm + mt * 16 + l15) * 32 + quad * 8]);                    \
    for (int nt = 0; nt < 4; nt++)                                                            \
      b[nt] = *(const short8*)(&Bs[(wn + nt * 16 + l15) * 32 + quad * 8]);                    \
    for (int mt = 0; mt < 4; mt++)                                                            \
      for (int nt = 0; nt < 4; nt++)                                                          \
        acc[mt][nt] = __builtin_amdgcn_mfma_f32_16x16x32_bf16(a[mt], b[nt], acc[mt][nt], 0, 0, 0); \
  }

__global__ __launch_bounds__(256) void gemm_proj(const u16* __restrict__ A,
                                                 const u16* __restrict__ Bt,
                                                 float* __restrict__ Co) {
  GEMM_BODY(1024)
#pragma unroll
  for (int mt = 0; mt < 4; mt++)
#pragma unroll
    for (int nt = 0; nt < 4; nt++)
#pragma unroll
      for (int r = 0; r < 4; r++) {
        int row = bm + wm + mt * 16 + quad * 4 + r;
        int col = bn + wn + nt * 16 + l15;
        Co[(size_t)row * 1024 + col] = acc[mt][nt][r];
      }
}

// ---------------- flash attention (unchanged) ----------------
__global__ __launch_bounds__(256, 2) void attn_kernel(const u16* __restrict__ qbuf,
                                                      const u16* __restrict__ kpack,
                                                      const u16* __restrict__ vpack,
                                                      u16* __restrict__ ctx) {
  int t = threadIdx.x;
  int wave = t >> 6, lane = t & 63, l31 = lane & 31, hi = lane >> 5;
  int bh = blockIdx.x;
  int s = (int)blockIdx.y * 4 + wave;
  int b = bh >> 4, h = bh & 15;
  int rowbase = b * 2048;
  int hi4 = hi * 4;

  const u16* kp = kpack + (size_t)bh * (32 * 4096) + lane * 8;
  const u16* vp = vpack + (size_t)bh * (32 * 4096) + lane * 8;

#pragma unroll
  for (int ph = 0; ph < 2; ph++) {
    int strip = ph ? 63 - s : s;
    int q0 = strip * 32;
    int q_lane = q0 + l31;

    const u16* qp = qbuf + (size_t)(rowbase + q_lane) * 1024 + h * 64 + hi * 8;
    short8 qf[4];
#pragma unroll
    for (int ks = 0; ks < 4; ks++) qf[ks] = *(const short8*)(qp + ks * 16);

    float l_run = 0.0f;
    f32x16 o[2];
    o[0] = (f32x16)0.0f; o[1] = (f32x16)0.0f;
    int ktmax = (q0 + 31) >> 6;

    for (int kt = 0; kt <= ktmax; kt++) {
      const u16* kb = kp + kt * 4096;
      const u16* vb = vp + kt * 4096;

      short8 ka[8], vv[8];
#pragma unroll
      for (int j = 0; j < 8; j++) {
        ka[j] = *(const short8*)(kb + j * 512);
        vv[j] = *(const short8*)(vb + j * 512);
      }

      f32x16 st0 = (f32x16)0.0f, st1 = (f32x16)0.0f;
#pragma unroll
      for (int ks = 0; ks < 4; ks++) {
        st0 = __builtin_amdgcn_mfma_f32_32x32x16_bf16(ka[ks], qf[ks], st0, 0, 0, 0);
        st1 = __builtin_amdgcn_mfma_f32_32x32x16_bf16(ka[4 + ks], qf[ks], st1, 0, 0, 0);
      }

      unsigned pk[2][8];
      if (kt == ktmax) {
#pragma unroll
        for (int ii = 0; ii < 8; ii++) {
          int key = kt * 64 + ((2 * ii) & 3) + 8 * ((2 * ii) >> 2) + hi4;
          float p00 = (key     <= q_lane) ? __builtin_amdgcn_exp2f(st0[2 * ii])     : 0.0f;
          float p01 = (key + 1 <= q_lane) ? __builtin_amdgcn_exp2f(st0[2 * ii + 1]) : 0.0f;
          float p10 = (key + 32 <= q_lane) ? __builtin_amdgcn_exp2f(st1[2 * ii])     : 0.0f;
          float p11 = (key + 33 <= q_lane) ? __builtin_amdgcn_exp2f(st1[2 * ii + 1]) : 0.0f;
          l_run += p00 + p01 + p10 + p11;
          pk[0][ii] = ((__float_as_uint(p00) + 0x8000u) >> 16) |
                      ((__float_as_uint(p01) + 0x8000u) & 0xffff0000u);
          pk[1][ii] = ((__float_as_uint(p10) + 0x8000u) >> 16) |
                      ((__float_as_uint(p11) + 0x8000u) & 0xffff0000u);
        }
      } else {
#pragma unroll
        for (int ii = 0; ii < 8; ii++) {
          float p00 = __builtin_amdgcn_exp2f(st0[2 * ii]);
          float p01 = __builtin_amdgcn_exp2f(st0[2 * ii + 1]);
          float p10 = __builtin_amdgcn_exp2f(st1[2 * ii]);
          float p11 = __builtin_amdgcn_exp2f(st1[2 * ii + 1]);
          l_run += p00 + p01 + p10 + p11;
          pk[0][ii] = ((__float_as_uint(p00) + 0x8000u) >> 16) |
                      ((__float_as_uint(p01) + 0x8000u) & 0xffff0000u);
          pk[1][ii] = ((__float_as_uint(p10) + 0x8000u) >> 16) |
                      ((__float_as_uint(p11) + 0x8000u) & 0xffff0000u);
        }
      }

      short8 pf[4];
#pragma unroll
      for (int ks2 = 0; ks2 < 4; ks2++) {
        int km = ks2 >> 1, h4 = (ks2 & 1) * 4;
        unsigned A0 = pk[km][h4 + 0], A1 = pk[km][h4 + 1];
        unsigned B0 = pk[km][h4 + 2], B1 = pk[km][h4 + 3];
        unsigned tA0 = (unsigned)__shfl_xor((int)A0, 32);
        unsigned tA1 = (unsigned)__shfl_xor((int)A1, 32);
        unsigned tB0 = (unsigned)__shfl_xor((int)B0, 32);
        unsigned tB1 = (unsigned)__shfl_xor((int)B1, 32);
        union { unsigned u[4]; short8 sh; } fr;
        fr.u[0] = hi ? tB0 : A0;
        fr.u[1] = hi ? tB1 : A1;
        fr.u[2] = hi ? B0 : tA0;
        fr.u[3] = hi ? B1 : tA1;
        pf[ks2] = fr.sh;
      }

#pragma unroll
      for (int am = 0; am < 2; am++)
#pragma unroll
        for (int ks2 = 0; ks2 < 4; ks2++)
          o[am] = __builtin_amdgcn_mfma_f32_32x32x16_bf16(vv[am * 4 + ks2], pf[ks2], o[am], 0, 0, 0);
    }

    float l_tot = l_run + __shfl_xor(l_run, 32);
    float inv = 1.0f / l_tot;
    size_t obase = (size_t)(rowbase + q_lane) * 1024 + h * 64;
#pragma unroll
    for (int am = 0; am < 2; am++)
#pragma unroll
      for (int k = 0; k < 4; k++) {
        ushort4 w;
        w.x = f2bf(o[am][4 * k + 0] * inv);
        w.y = f2bf(o[am][4 * k + 1] * inv);
        w.z = f2bf(o[am][4 * k + 2] * inv);
        w.w = f2bf(o[am][4 * k + 3] * inv);
        *(ushort4*)&ctx[obase + am * 32 + k * 8 + hi4] = w;
      }
  }
}

// ---------------- launch ----------------
// ws layout (88 MB):
//   0-16 qbuf | 16-32 kpack | 32-48 vpack | 48-64 xb | 64-80 ctx
//   80-86 wqkvT | 86-88 wprojT
extern "C" void kernel_launch(void* const* d_in, const int* in_sizes, int n_in,
                              void* d_out, int out_size, void* d_ws, size_t ws_size,
                              hipStream_t stream) {
  const float* x      = (const float*)d_in[0];
  const float* w_qkv  = (const float*)d_in[1];
  const float* w_proj = (const float*)d_in[2];
  float* out = (float*)d_out;

  char* ws = (char*)d_ws;
  const size_t MB = 1024 * 1024;
  u16* qbuf   = (u16*)(ws);
  u16* kpack  = (u16*)(ws + 16 * MB);
  u16* vpack  = (u16*)(ws + 32 * MB);
  u16* xb     = (u16*)(ws + 48 * MB);
  u16* ctx    = (u16*)(ws + 64 * MB);
  u16* wqkvT  = (u16*)(ws + 80 * MB);
  u16* wprojT = (u16*)(ws + 86 * MB);

  cast_kernel<<<8192, 256, 0, stream>>>(x, xb, 2097152);
  tcast_kernel<<<dim3(96, 32), 256, 0, stream>>>(w_qkv, wqkvT, 1024, 3072);
  tcast_kernel<<<dim3(32, 32), 256, 0, stream>>>(w_proj, wprojT, 1024, 1024);

  gemm_qkv<<<dim3(384), 512, 0, stream>>>(xb, wqkvT, qbuf, kpack, vpack);
  attn_kernel<<<dim3(64, 8), 256, 0, stream>>>(qbuf, kpack, vpack, ctx);
  gemm_proj<<<dim3(8, 64), 256, 0, stream>>>(ctx, wprojT, out);
}

// Round 7
// 234.520 us; speedup vs baseline: 1.1010x; 1.0352x over previous
//
#include <hip/hip_runtime.h>
#include <hip/hip_bf16.h>

typedef unsigned short u16;
typedef __attribute__((ext_vector_type(8))) short short8;
typedef __attribute__((ext_vector_type(4))) float f32x4;
typedef __attribute__((ext_vector_type(16))) float f32x16;

__device__ inline u16 f2bf(float f) {
  unsigned u = __float_as_uint(f);
  u += 0x7fffu + ((u >> 16) & 1u);   // round-to-nearest-even
  return (u16)(u >> 16);
}

// ---------------- fused prep: cast x + transpose-cast both weights ----------------
// blocks [0,8192): cast x (fp32->bf16, x4); [8192,11264): tcast w_qkv; [11264,12288): tcast w_proj
__global__ __launch_bounds__(256) void prep_kernel(const float* __restrict__ x,
                                                   u16* __restrict__ xb,
                                                   const float* __restrict__ wq,
                                                   u16* __restrict__ wqT,
                                                   const float* __restrict__ wp,
                                                   u16* __restrict__ wpT) {
  __shared__ float tile[32][33];
  int bid = blockIdx.x;
  if (bid < 8192) {
    int i = bid * 256 + threadIdx.x;
    float4 v = ((const float4*)x)[i];
    ushort4 o;
    o.x = f2bf(v.x); o.y = f2bf(v.y); o.z = f2bf(v.z); o.w = f2bf(v.w);
    ((ushort4*)xb)[i] = o;
    return;
  }
  const float* in; u16* out; int N, bx, by;
  if (bid < 11264) {
    int idx = bid - 8192;
    in = wq; out = wqT; N = 3072;
    bx = (idx % 96) * 32; by = (idx / 96) * 32;
  } else {
    int idx = bid - 11264;
    in = wp; out = wpT; N = 1024;
    bx = (idx % 32) * 32; by = (idx / 32) * 32;
  }
  int tx = threadIdx.x & 31, ty = threadIdx.x >> 5;
#pragma unroll
  for (int i = 0; i < 4; i++) {
    int r = ty + i * 8;
    tile[r][tx] = in[(size_t)(by + r) * N + bx + tx];
  }
  __syncthreads();
#pragma unroll
  for (int i = 0; i < 4; i++) {
    int r = ty + i * 8;
    out[(size_t)(bx + r) * 1024 + by + tx] = f2bf(tile[tx][r]);
  }
}

// ==================== gemm_qkv: UNCHANGED from round 5 (verified) ==================
#define VMWAIT(n) asm volatile("s_waitcnt vmcnt(" #n ")" ::: "memory")
#define LGKM0() asm volatile("s_waitcnt lgkmcnt(0)" ::: "memory")
#define BAR() asm volatile("s_barrier" ::: "memory")

__device__ __forceinline__ void gll16(const u16* g, u16* l) {
  __builtin_amdgcn_global_load_lds((const __attribute__((address_space(1))) unsigned*)g,
                                   (__attribute__((address_space(3))) unsigned*)l, 16, 0, 0);
}

__global__ __launch_bounds__(512, 2) void gemm_qkv(const u16* __restrict__ A,
                                                   const u16* __restrict__ Bt,
                                                   u16* __restrict__ qb,
                                                   u16* __restrict__ kpack,
                                                   u16* __restrict__ vpack) {
  __shared__ u16 lds[65536];  // 128 KB: buffer b at b*32768 u16
  int tid = threadIdx.x;
  int w = tid >> 6, lane = tid & 63, l15 = lane & 15, quad = lane >> 4;
  int wr = w >> 2, wc = w & 3;

  int bid = blockIdx.x;
  int wgid = (bid & 7) * 48 + (bid >> 3);
  int bm = (wgid / 12) * 256;
  int bn3 = (wgid % 12) * 256;

  int srow = lane >> 2;
  int kswz = ((lane & 3) * 8) ^ ((lane >> 5) << 4);
  const u16* gA0 = A + (size_t)(bm + w * 16 + srow) * 1024 + kswz;
  const u16* gA1 = A + (size_t)(bm + 128 + w * 16 + srow) * 1024 + kswz;
  const u16* gB0 = Bt + (size_t)(bn3 + w * 16 + srow) * 1024 + kswz;
  const u16* gB1 = Bt + (size_t)(bn3 + 128 + w * 16 + srow) * 1024 + kswz;

  int kq = (quad * 8) ^ ((l15 & 8) << 1);
  int aoff = wr * 8192 + l15 * 32 + kq;
  int boff = 16384 + (wc >> 1) * 8192 + (wc & 1) * 2048 + l15 * 32 + kq;

  f32x4 acc[8][4];
#pragma unroll
  for (int m = 0; m < 8; m++)
#pragma unroll
    for (int n = 0; n < 4; n++) acc[m][n] = (f32x4)0.0f;

  short8 a[8], bA[4], bB[4];

#define STAGE_AH0(T)                                          \
  do {                                                        \
    u16* d_ = lds + ((T) & 1) * 32768 + w * 512;              \
    gll16(gA0 + (size_t)(T) * 64, d_);                        \
    gll16(gA0 + (size_t)(T) * 64 + 32, d_ + 4096);            \
  } while (0)
#define STAGE_AH1(T)                                          \
  do {                                                        \
    u16* d_ = lds + ((T) & 1) * 32768 + 8192 + w * 512;       \
    gll16(gA1 + (size_t)(T) * 64, d_);                        \
    gll16(gA1 + (size_t)(T) * 64 + 32, d_ + 4096);            \
  } while (0)
#define STAGE_BH0(T)                                          \
  do {                                                        \
    u16* d_ = lds + ((T) & 1) * 32768 + 16384 + w * 512;      \
    gll16(gB0 + (size_t)(T) * 64, d_);                        \
    gll16(gB0 + (size_t)(T) * 64 + 32, d_ + 4096);            \
  } while (0)
#define STAGE_BH1(T)                                          \
  do {                                                        \
    u16* d_ = lds + ((T) & 1) * 32768 + 24576 + w * 512;      \
    gll16(gB1 + (size_t)(T) * 64, d_);                        \
    gll16(gB1 + (size_t)(T) * 64 + 32, d_ + 4096);            \
  } while (0)

#define MFMA16(NLO, BV0, BV1)                                                                  \
  do {                                                                                         \
    __builtin_amdgcn_s_setprio(1);                                                             \
    _Pragma("unroll") for (int m = 0; m < 8; m++)                                              \
        acc[m][NLO] = __builtin_amdgcn_mfma_f32_16x16x32_bf16(a[m], BV0, acc[m][NLO], 0, 0, 0);\
    _Pragma("unroll") for (int m = 0; m < 8; m++)                                              \
        acc[m][NLO + 1] =                                                                      \
            __builtin_amdgcn_mfma_f32_16x16x32_bf16(a[m], BV1, acc[m][NLO + 1], 0, 0, 0);      \
    __builtin_amdgcn_s_setprio(0);                                                             \
  } while (0)

#define PHASE1(T, DOSTG)                                                                       \
  do {                                                                                         \
    const u16* bc_ = lds + ((T) & 1) * 32768;                                                  \
    _Pragma("unroll") for (int m = 0; m < 8; m++)                                              \
        a[m] = *(const short8*)(bc_ + aoff + m * 512);                                         \
    if (DOSTG) STAGE_AH0((T) + 1);                                                             \
    BAR(); LGKM0();                                                                            \
    MFMA16(0, bA[0], bA[1]);                                                                   \
    BAR();                                                                                     \
  } while (0)

#define PHASE2(T, DOSTG)                                                                       \
  do {                                                                                         \
    const u16* bc_ = lds + ((T) & 1) * 32768;                                                  \
    _Pragma("unroll") for (int n = 0; n < 4; n++)                                              \
        bB[n] = *(const short8*)(bc_ + boff + 4096 + n * 512);                                 \
    if (DOSTG) STAGE_AH1((T) + 1);                                                             \
    BAR(); LGKM0();                                                                            \
    MFMA16(2, bA[2], bA[3]);                                                                   \
    BAR();                                                                                     \
  } while (0)

#define PHASE3(T, DOSTG, VMN)                                                                  \
  do {                                                                                         \
    const u16* bc_ = lds + ((T) & 1) * 32768;                                                  \
    _Pragma("unroll") for (int m = 0; m < 8; m++)                                              \
        a[m] = *(const short8*)(bc_ + aoff + 4096 + m * 512);                                  \
    if (DOSTG) STAGE_BH0((T) + 2);                                                             \
    BAR(); LGKM0();                                                                            \
    MFMA16(0, bB[0], bB[1]);                                                                   \
    VMN;                                                                                       \
    BAR();                                                                                     \
  } while (0)

#define PHASE4(T, DORD, DOSTG, VMN)                                                            \
  do {                                                                                         \
    if (DORD) {                                                                                \
      const u16* bn_ = lds + (((T) + 1) & 1) * 32768;                                          \
      _Pragma("unroll") for (int n = 0; n < 4; n++)                                            \
          bA[n] = *(const short8*)(bn_ + boff + n * 512);                                      \
    }                                                                                          \
    if (DOSTG) STAGE_BH1((T) + 2);                                                             \
    BAR(); LGKM0();                                                                            \
    MFMA16(2, bB[2], bB[3]);                                                                   \
    VMN;                                                                                       \
    BAR();                                                                                     \
  } while (0)

  STAGE_BH0(0); STAGE_BH1(0); STAGE_AH0(0); STAGE_AH1(0); STAGE_BH0(1); STAGE_BH1(1);
  VMWAIT(4);
  BAR();
  {
    const u16* bc_ = lds;
#pragma unroll
    for (int n = 0; n < 4; n++) bA[n] = *(const short8*)(bc_ + boff + n * 512);
  }

  for (int T = 0; T < 14; ++T) {
    PHASE1(T, 1);
    PHASE2(T, 1);
    PHASE3(T, 1, VMWAIT(6));
    PHASE4(T, 1, 1, VMWAIT(4));
  }
  PHASE1(14, 1);
  PHASE2(14, 1);
  PHASE3(14, 0, VMWAIT(4));
  PHASE4(14, 1, 0, VMWAIT(0));
  PHASE1(15, 0);
  PHASE2(15, 0);
  PHASE3(15, 0, (void)0);
  PHASE4(15, 0, 0, (void)0);

#undef PHASE1
#undef PHASE2
#undef PHASE3
#undef PHASE4
#undef MFMA16
#undef STAGE_AH0
#undef STAGE_AH1
#undef STAGE_BH0
#undef STAGE_BH1

  if (bn3 < 1024) {
    float scl = 0.18033688011112f;
    int rbase = bm + wr * 128 + quad * 4;
    int cbase = bn3 + wc * 64 + l15;
#pragma unroll
    for (int m = 0; m < 8; m++)
#pragma unroll
      for (int n = 0; n < 4; n++)
#pragma unroll
        for (int r = 0; r < 4; r++)
          qb[(size_t)(rbase + m * 16 + r) * 1024 + cbase + n * 16] = f2bf(acc[m][n][r] * scl);
  } else {
    int bnl = bn3 & 1023;
    int h = (bnl >> 6) + wc;
    int bh = (bm >> 11) * 16 + h;
    int ktb = ((bm & 2047) >> 6) + wr * 2;
    if (bn3 < 2048) {
      int lhi = ((l15 >> 3) & 1) * 32;
      int e = l15 & 7;
#pragma unroll
      for (int m = 0; m < 8; m++) {
        u16* kd = kpack + ((size_t)bh * 32 + ktb + (m >> 2)) * 4096;
        int krb = (m & 3) * 16 + quad * 4;
        int jm = (krb >> 5) * 4;
        int l31b = krb & 31;
#pragma unroll
        for (int n = 0; n < 4; n++)
#pragma unroll
          for (int r = 0; r < 4; r++) {
            int off = (jm + n) * 512 + (l31b + r + lhi) * 8 + e;
            kd[off] = f2bf(acc[m][n][r]);
          }
      }
    } else {
      int e0 = (quad & 1) * 4;
      int hi5 = (quad >> 1) * 32;
#pragma unroll
      for (int m = 0; m < 8; m++) {
        u16* vd = vpack + ((size_t)bh * 32 + ktb + (m >> 2)) * 4096;
#pragma unroll
        for (int n = 0; n < 4; n++) {
          int off = ((n >> 1) * 4 + (m & 3)) * 512 +
                    ((n & 1) * 16 + l15 + hi5) * 8 + e0;
          ushort4 wv;
          wv.x = f2bf(acc[m][n][0]);
          wv.y = f2bf(acc[m][n][1]);
          wv.z = f2bf(acc[m][n][2]);
          wv.w = f2bf(acc[m][n][3]);
          *(ushort4*)(vd + off) = wv;
        }
      }
    }
  }
}

// ==================== gemm_proj: 256x128, BK=64, 4-phase, ONE full round ===========
// 256 blocks (=CU count), 512 thr / 8 waves (4M x 2N); per-wave C = 64x64 = acc[4][4].
// LDS 96KB: 2 buffers x (A 256x64 = 32KB | B 128x64 = 16KB). Same swizzle scheme as
// gemm_qkv (verified). Stage cadence per K-tile: P1 A-lo(T+1), P2 A-hi(T+1),
// P3 B(T+2), P4 none (6 gloads/thread/tile). Counted vmcnt: vm(6)@P3 retires B(T+1)
// (read by P4); vm(2)@P4 retires A(T+1) (read by P1(T+1)). Tail 4 -> 0.
__global__ __launch_bounds__(512, 2) void gemm_proj(const u16* __restrict__ A,
                                                    const u16* __restrict__ Bt,
                                                    float* __restrict__ Co) {
  __shared__ u16 lds[49152];  // 96 KB: buffer b at b*24576 u16; A at +0, B at +16384
  int tid = threadIdx.x;
  int w = tid >> 6, lane = tid & 63, l15 = lane & 15, quad = lane >> 4;
  int wr = w >> 1, wc = w & 1;

  // bijective XCD swizzle (256 % 8 == 0); consecutive wgid share the A panel
  int bid = blockIdx.x;
  int wgid = (bid & 7) * 32 + (bid >> 3);
  int bm = (wgid >> 3) * 256;
  int bn = (wgid & 7) * 128;

  int srow = lane >> 2;
  int kswz = ((lane & 3) * 8) ^ ((lane >> 5) << 4);
  const u16* gA0 = A + (size_t)(bm + w * 16 + srow) * 1024 + kswz;
  const u16* gA1 = A + (size_t)(bm + 128 + w * 16 + srow) * 1024 + kswz;
  const u16* gB0 = Bt + (size_t)(bn + w * 16 + srow) * 1024 + kswz;

  int kq = (quad * 8) ^ ((l15 & 8) << 1);
  int aoff = (wr >> 1) * 8192 + (wr & 1) * 2048 + l15 * 32 + kq;  // + mt*512
  int boff = 16384 + wc * 2048 + l15 * 32 + kq;                   // + n*512

  f32x4 acc[4][4];
#pragma unroll
  for (int m = 0; m < 4; m++)
#pragma unroll
    for (int n = 0; n < 4; n++) acc[m][n] = (f32x4)0.0f;

  short8 a[4], bA[4], bB[4];

#define PSTG_ALO(T)                                           \
  do {                                                        \
    u16* d_ = lds + ((T) & 1) * 24576 + w * 512;              \
    gll16(gA0 + (size_t)(T) * 64, d_);                        \
    gll16(gA0 + (size_t)(T) * 64 + 32, d_ + 4096);            \
  } while (0)
#define PSTG_AHI(T)                                           \
  do {                                                        \
    u16* d_ = lds + ((T) & 1) * 24576 + 8192 + w * 512;       \
    gll16(gA1 + (size_t)(T) * 64, d_);                        \
    gll16(gA1 + (size_t)(T) * 64 + 32, d_ + 4096);            \
  } while (0)
#define PSTG_B(T)                                             \
  do {                                                        \
    u16* d_ = lds + ((T) & 1) * 24576 + 16384 + w * 512;      \
    gll16(gB0 + (size_t)(T) * 64, d_);                        \
    gll16(gB0 + (size_t)(T) * 64 + 32, d_ + 4096);            \
  } while (0)

#define MFMA8(NLO, BV0, BV1)                                                                   \
  do {                                                                                         \
    __builtin_amdgcn_s_setprio(1);                                                             \
    _Pragma("unroll") for (int m = 0; m < 4; m++)                                              \
        acc[m][NLO] = __builtin_amdgcn_mfma_f32_16x16x32_bf16(a[m], BV0, acc[m][NLO], 0, 0, 0);\
    _Pragma("unroll") for (int m = 0; m < 4; m++)                                              \
        acc[m][NLO + 1] =                                                                      \
            __builtin_amdgcn_mfma_f32_16x16x32_bf16(a[m], BV1, acc[m][NLO + 1], 0, 0, 0);      \
    __builtin_amdgcn_s_setprio(0);                                                             \
  } while (0)

#define PPH1(T, DOSTG)                                                                         \
  do {                                                                                         \
    const u16* bc_ = lds + ((T) & 1) * 24576;                                                  \
    _Pragma("unroll") for (int m = 0; m < 4; m++)                                              \
        a[m] = *(const short8*)(bc_ + aoff + m * 512);                                         \
    if (DOSTG) PSTG_ALO((T) + 1);                                                              \
    BAR(); LGKM0();                                                                            \
    MFMA8(0, bA[0], bA[1]);                                                                    \
    BAR();                                                                                     \
  } while (0)

#define PPH2(T, DOSTG)                                                                         \
  do {                                                                                         \
    const u16* bc_ = lds + ((T) & 1) * 24576;                                                  \
    _Pragma("unroll") for (int n = 0; n < 4; n++)                                              \
        bB[n] = *(const short8*)(bc_ + boff + 4096 + n * 512);                                 \
    if (DOSTG) PSTG_AHI((T) + 1);                                                              \
    BAR(); LGKM0();                                                                            \
    MFMA8(2, bA[2], bA[3]);                                                                    \
    BAR();                                                                                     \
  } while (0)

#define PPH3(T, DOSTG, VMN)                                                                    \
  do {                                                                                         \
    const u16* bc_ = lds + ((T) & 1) * 24576;                                                  \
    _Pragma("unroll") for (int m = 0; m < 4; m++)                                              \
        a[m] = *(const short8*)(bc_ + aoff + 4096 + m * 512);                                  \
    if (DOSTG) PSTG_B((T) + 2);                                                                \
    BAR(); LGKM0();                                                                            \
    MFMA8(0, bB[0], bB[1]);                                                                    \
    VMN;                                                                                       \
    BAR();                                                                                     \
  } while (0)

#define PPH4(T, DORD, VMN)                                                                     \
  do {                                                                                         \
    if (DORD) {                                                                                \
      const u16* bn_ = lds + (((T) + 1) & 1) * 24576;                                          \
      _Pragma("unroll") for (int n = 0; n < 4; n++)                                            \
          bA[n] = *(const short8*)(bn_ + boff + n * 512);                                      \
    }                                                                                          \
    BAR(); LGKM0();                                                                            \
    MFMA8(2, bB[2], bB[3]);                                                                    \
    VMN;                                                                                       \
    BAR();                                                                                     \
  } while (0)

  // prologue: A(0), B(0), B(1); retire A(0)+B(0), keep B(1); pre-read bA@buf0
  PSTG_ALO(0); PSTG_AHI(0); PSTG_B(0); PSTG_B(1);
  VMWAIT(2);
  BAR();
  {
    const u16* bc_ = lds;
#pragma unroll
    for (int n = 0; n < 4; n++) bA[n] = *(const short8*)(bc_ + boff + n * 512);
  }

  for (int T = 0; T < 14; ++T) {
    PPH1(T, 1);
    PPH2(T, 1);
    PPH3(T, 1, VMWAIT(6));
    PPH4(T, 1, VMWAIT(2));
  }
  PPH1(14, 1);
  PPH2(14, 1);
  PPH3(14, 0, VMWAIT(4));   // retire B(15); keep A(15)
  PPH4(14, 1, VMWAIT(0));   // retire A(15)
  PPH1(15, 0);
  PPH2(15, 0);
  PPH3(15, 0, (void)0);
  PPH4(15, 0, (void)0);

#undef PPH1
#undef PPH2
#undef PPH3
#undef PPH4
#undef MFMA8
#undef PSTG_ALO
#undef PSTG_AHI
#undef PSTG_B

  // epilogue: fp32 out, row-major
  int rbase = bm + wr * 64 + quad * 4;
  int cbase = bn + wc * 64 + l15;
#pragma unroll
  for (int m = 0; m < 4; m++)
#pragma unroll
    for (int n = 0; n < 4; n++)
#pragma unroll
      for (int r = 0; r < 4; r++)
        Co[(size_t)(rbase + m * 16 + r) * 1024 + cbase + n * 16] = acc[m][n][r];
}

// ---------------- flash attention (round-5 verified: bit-trick packing) ----------------
__global__ __launch_bounds__(256, 2) void attn_kernel(const u16* __restrict__ qbuf,
                                                      const u16* __restrict__ kpack,
                                                      const u16* __restrict__ vpack,
                                                      u16* __restrict__ ctx) {
  int t = threadIdx.x;
  int wave = t >> 6, lane = t & 63, l31 = lane & 31, hi = lane >> 5;
  int bh = blockIdx.x;
  int s = (int)blockIdx.y * 4 + wave;
  int b = bh >> 4, h = bh & 15;
  int rowbase = b * 2048;
  int hi4 = hi * 4;

  const u16* kp = kpack + (size_t)bh * (32 * 4096) + lane * 8;
  const u16* vp = vpack + (size_t)bh * (32 * 4096) + lane * 8;

#pragma unroll
  for (int ph = 0; ph < 2; ph++) {
    int strip = ph ? 63 - s : s;
    int q0 = strip * 32;
    int q_lane = q0 + l31;

    const u16* qp = qbuf + (size_t)(rowbase + q_lane) * 1024 + h * 64 + hi * 8;
    short8 qf[4];
#pragma unroll
    for (int ks = 0; ks < 4; ks++) qf[ks] = *(const short8*)(qp + ks * 16);

    float l_run = 0.0f;
    f32x16 o[2];
    o[0] = (f32x16)0.0f; o[1] = (f32x16)0.0f;
    int ktmax = (q0 + 31) >> 6;

    for (int kt = 0; kt <= ktmax; kt++) {
      const u16* kb = kp + kt * 4096;
      const u16* vb = vp + kt * 4096;

      short8 ka[8], vv[8];
#pragma unroll
      for (int j = 0; j < 8; j++) {
        ka[j] = *(const short8*)(kb + j * 512);
        vv[j] = *(const short8*)(vb + j * 512);
      }

      f32x16 st0 = (f32x16)0.0f, st1 = (f32x16)0.0f;
#pragma unroll
      for (int ks = 0; ks < 4; ks++) {
        st0 = __builtin_amdgcn_mfma_f32_32x32x16_bf16(ka[ks], qf[ks], st0, 0, 0, 0);
        st1 = __builtin_amdgcn_mfma_f32_32x32x16_bf16(ka[4 + ks], qf[ks], st1, 0, 0, 0);
      }

      unsigned pk[2][8];
      if (kt == ktmax) {
#pragma unroll
        for (int ii = 0; ii < 8; ii++) {
          int key = kt * 64 + ((2 * ii) & 3) + 8 * ((2 * ii) >> 2) + hi4;
          float p00 = (key     <= q_lane) ? __builtin_amdgcn_exp2f(st0[2 * ii])     : 0.0f;
          float p01 = (key + 1 <= q_lane) ? __builtin_amdgcn_exp2f(st0[2 * ii + 1]) : 0.0f;
          float p10 = (key + 32 <= q_lane) ? __builtin_amdgcn_exp2f(st1[2 * ii])     : 0.0f;
          float p11 = (key + 33 <= q_lane) ? __builtin_amdgcn_exp2f(st1[2 * ii + 1]) : 0.0f;
          l_run += p00 + p01 + p10 + p11;
          pk[0][ii] = ((__float_as_uint(p00) + 0x8000u) >> 16) |
                      ((__float_as_uint(p01) + 0x8000u) & 0xffff0000u);
          pk[1][ii] = ((__float_as_uint(p10) + 0x8000u) >> 16) |
                      ((__float_as_uint(p11) + 0x8000u) & 0xffff0000u);
        }
      } else {
#pragma unroll
        for (int ii = 0; ii < 8; ii++) {
          float p00 = __builtin_amdgcn_exp2f(st0[2 * ii]);
          float p01 = __builtin_amdgcn_exp2f(st0[2 * ii + 1]);
          float p10 = __builtin_amdgcn_exp2f(st1[2 * ii]);
          float p11 = __builtin_amdgcn_exp2f(st1[2 * ii + 1]);
          l_run += p00 + p01 + p10 + p11;
          pk[0][ii] = ((__float_as_uint(p00) + 0x8000u) >> 16) |
                      ((__float_as_uint(p01) + 0x8000u) & 0xffff0000u);
          pk[1][ii] = ((__float_as_uint(p10) + 0x8000u) >> 16) |
                      ((__float_as_uint(p11) + 0x8000u) & 0xffff0000u);
        }
      }

      short8 pf[4];
#pragma unroll
      for (int ks2 = 0; ks2 < 4; ks2++) {
        int km = ks2 >> 1, h4 = (ks2 & 1) * 4;
        unsigned A0 = pk[km][h4 + 0], A1 = pk[km][h4 + 1];
        unsigned B0 = pk[km][h4 + 2], B1 = pk[km][h4 + 3];
        unsigned tA0 = (unsigned)__shfl_xor((int)A0, 32);
        unsigned tA1 = (unsigned)__shfl_xor((int)A1, 32);
        unsigned tB0 = (unsigned)__shfl_xor((int)B0, 32);
        unsigned tB1 = (unsigned)__shfl_xor((int)B1, 32);
        union { unsigned u[4]; short8 sh; } fr;
        fr.u[0] = hi ? tB0 : A0;
        fr.u[1] = hi ? tB1 : A1;
        fr.u[2] = hi ? B0 : tA0;
        fr.u[3] = hi ? B1 : tA1;
        pf[ks2] = fr.sh;
      }

#pragma unroll
      for (int am = 0; am < 2; am++)
#pragma unroll
        for (int ks2 = 0; ks2 < 4; ks2++)
          o[am] = __builtin_amdgcn_mfma_f32_32x32x16_bf16(vv[am * 4 + ks2], pf[ks2], o[am], 0, 0, 0);
    }

    float l_tot = l_run + __shfl_xor(l_run, 32);
    float inv = 1.0f / l_tot;
    size_t obase = (size_t)(rowbase + q_lane) * 1024 + h * 64;
#pragma unroll
    for (int am = 0; am < 2; am++)
#pragma unroll
      for (int k = 0; k < 4; k++) {
        ushort4 w;
        w.x = f2bf(o[am][4 * k + 0] * inv);
        w.y = f2bf(o[am][4 * k + 1] * inv);
        w.z = f2bf(o[am][4 * k + 2] * inv);
        w.w = f2bf(o[am][4 * k + 3] * inv);
        *(ushort4*)&ctx[obase + am * 32 + k * 8 + hi4] = w;
      }
  }
}

// ---------------- launch ----------------
// ws layout (88 MB):
//   0-16 qbuf | 16-32 kpack | 32-48 vpack | 48-64 xb | 64-80 ctx
//   80-86 wqkvT | 86-88 wprojT
extern "C" void kernel_launch(void* const* d_in, const int* in_sizes, int n_in,
                              void* d_out, int out_size, void* d_ws, size_t ws_size,
                              hipStream_t stream) {
  const float* x      = (const float*)d_in[0];
  const float* w_qkv  = (const float*)d_in[1];
  const float* w_proj = (const float*)d_in[2];
  float* out = (float*)d_out;

  char* ws = (char*)d_ws;
  const size_t MB = 1024 * 1024;
  u16* qbuf   = (u16*)(ws);
  u16* kpack  = (u16*)(ws + 16 * MB);
  u16* vpack  = (u16*)(ws + 32 * MB);
  u16* xb     = (u16*)(ws + 48 * MB);
  u16* ctx    = (u16*)(ws + 64 * MB);
  u16* wqkvT  = (u16*)(ws + 80 * MB);
  u16* wprojT = (u16*)(ws + 86 * MB);

  prep_kernel<<<12288, 256, 0, stream>>>(x, xb, w_qkv, wqkvT, w_proj, wprojT);
  gemm_qkv<<<dim3(384), 512, 0, stream>>>(xb, wqkvT, qbuf, kpack, vpack);
  attn_kernel<<<dim3(64, 8), 256, 0, stream>>>(qbuf, kpack, vpack, ctx);
  gemm_proj<<<dim3(256), 512, 0, stream>>>(ctx, wprojT, out);
}

// Round 8
// 229.112 us; speedup vs baseline: 1.1270x; 1.0236x over previous
//
#include <hip/hip_runtime.h>
#include <hip/hip_bf16.h>

typedef unsigned short u16;
typedef __attribute__((ext_vector_type(8))) short short8;
typedef __attribute__((ext_vector_type(4))) float f32x4;
typedef __attribute__((ext_vector_type(16))) float f32x16;

__device__ inline u16 f2bf(float f) {
  unsigned u = __float_as_uint(f);
  u += 0x7fffu + ((u >> 16) & 1u);   // round-to-nearest-even
  return (u16)(u >> 16);
}

// ---------------- fused prep: cast x + transpose-cast both weights ----------------
__global__ __launch_bounds__(256) void prep_kernel(const float* __restrict__ x,
                                                   u16* __restrict__ xb,
                                                   const float* __restrict__ wq,
                                                   u16* __restrict__ wqT,
                                                   const float* __restrict__ wp,
                                                   u16* __restrict__ wpT) {
  __shared__ float tile[32][33];
  int bid = blockIdx.x;
  if (bid < 8192) {
    int i = bid * 256 + threadIdx.x;
    float4 v = ((const float4*)x)[i];
    ushort4 o;
    o.x = f2bf(v.x); o.y = f2bf(v.y); o.z = f2bf(v.z); o.w = f2bf(v.w);
    ((ushort4*)xb)[i] = o;
    return;
  }
  const float* in; u16* out; int N, bx, by;
  if (bid < 11264) {
    int idx = bid - 8192;
    in = wq; out = wqT; N = 3072;
    bx = (idx % 96) * 32; by = (idx / 96) * 32;
  } else {
    int idx = bid - 11264;
    in = wp; out = wpT; N = 1024;
    bx = (idx % 32) * 32; by = (idx / 32) * 32;
  }
  int tx = threadIdx.x & 31, ty = threadIdx.x >> 5;
#pragma unroll
  for (int i = 0; i < 4; i++) {
    int r = ty + i * 8;
    tile[r][tx] = in[(size_t)(by + r) * N + bx + tx];
  }
  __syncthreads();
#pragma unroll
  for (int i = 0; i < 4; i++) {
    int r = ty + i * 8;
    out[(size_t)(bx + r) * 1024 + by + tx] = f2bf(tile[tx][r]);
  }
}

// ==================== gemm_qkv: 256x256, BK=64, SINGLE-BARRIER phases ==============
// Phase = [stage; counted-vmcnt; s_barrier; ds_reads; lgkm0; MFMA] — 64 barriers
// (was 128). The one BAR both publishes vm-retired stages and orders reads-before-
// overwrite (reads drained by reader's lgkm >=1 barrier before the region's stage).
// Stages: P1 AH0(T+1), P2 AH1(T+1), P4 BH0+BH1(T+2). Waits: vm(6)@P1 retires A(T);
// vm(8)@P4 retires B(T+1). Prologue B0,A0,B1 + vm(4); tail vm(6)/vm(4)/vm(0).
#define VMWAIT(n) asm volatile("s_waitcnt vmcnt(" #n ")" ::: "memory")
#define LGKM0() asm volatile("s_waitcnt lgkmcnt(0)" ::: "memory")
#define BAR() asm volatile("s_barrier" ::: "memory")

__device__ __forceinline__ void gll16(const u16* g, u16* l) {
  __builtin_amdgcn_global_load_lds((const __attribute__((address_space(1))) unsigned*)g,
                                   (__attribute__((address_space(3))) unsigned*)l, 16, 0, 0);
}

__global__ __launch_bounds__(512, 2) void gemm_qkv(const u16* __restrict__ A,
                                                   const u16* __restrict__ Bt,
                                                   u16* __restrict__ qb,
                                                   u16* __restrict__ kpack,
                                                   u16* __restrict__ vpack) {
  __shared__ u16 lds[65536];  // 128 KB: buffer b at b*32768 u16
  int tid = threadIdx.x;
  int w = tid >> 6, lane = tid & 63, l15 = lane & 15, quad = lane >> 4;
  int wr = w >> 2, wc = w & 3;

  int bid = blockIdx.x;
  int wgid = (bid & 7) * 48 + (bid >> 3);
  int bm = (wgid / 12) * 256;
  int bn3 = (wgid % 12) * 256;

  int srow = lane >> 2;
  int kswz = ((lane & 3) * 8) ^ ((lane >> 5) << 4);
  const u16* gA0 = A + (size_t)(bm + w * 16 + srow) * 1024 + kswz;
  const u16* gA1 = A + (size_t)(bm + 128 + w * 16 + srow) * 1024 + kswz;
  const u16* gB0 = Bt + (size_t)(bn3 + w * 16 + srow) * 1024 + kswz;
  const u16* gB1 = Bt + (size_t)(bn3 + 128 + w * 16 + srow) * 1024 + kswz;

  int kq = (quad * 8) ^ ((l15 & 8) << 1);
  int aoff = wr * 8192 + l15 * 32 + kq;
  int boff = 16384 + (wc >> 1) * 8192 + (wc & 1) * 2048 + l15 * 32 + kq;

  f32x4 acc[8][4];
#pragma unroll
  for (int m = 0; m < 8; m++)
#pragma unroll
    for (int n = 0; n < 4; n++) acc[m][n] = (f32x4)0.0f;

  short8 a[8], bA[4], bB[4];

#define STAGE_AH0(T)                                          \
  do {                                                        \
    u16* d_ = lds + ((T) & 1) * 32768 + w * 512;              \
    gll16(gA0 + (size_t)(T) * 64, d_);                        \
    gll16(gA0 + (size_t)(T) * 64 + 32, d_ + 4096);            \
  } while (0)
#define STAGE_AH1(T)                                          \
  do {                                                        \
    u16* d_ = lds + ((T) & 1) * 32768 + 8192 + w * 512;       \
    gll16(gA1 + (size_t)(T) * 64, d_);                        \
    gll16(gA1 + (size_t)(T) * 64 + 32, d_ + 4096);            \
  } while (0)
#define STAGE_BH0(T)                                          \
  do {                                                        \
    u16* d_ = lds + ((T) & 1) * 32768 + 16384 + w * 512;      \
    gll16(gB0 + (size_t)(T) * 64, d_);                        \
    gll16(gB0 + (size_t)(T) * 64 + 32, d_ + 4096);            \
  } while (0)
#define STAGE_BH1(T)                                          \
  do {                                                        \
    u16* d_ = lds + ((T) & 1) * 32768 + 24576 + w * 512;      \
    gll16(gB1 + (size_t)(T) * 64, d_);                        \
    gll16(gB1 + (size_t)(T) * 64 + 32, d_ + 4096);            \
  } while (0)

#define MFMA16(NLO, BV0, BV1)                                                                  \
  do {                                                                                         \
    __builtin_amdgcn_s_setprio(1);                                                             \
    _Pragma("unroll") for (int m = 0; m < 8; m++)                                              \
        acc[m][NLO] = __builtin_amdgcn_mfma_f32_16x16x32_bf16(a[m], BV0, acc[m][NLO], 0, 0, 0);\
    _Pragma("unroll") for (int m = 0; m < 8; m++)                                              \
        acc[m][NLO + 1] =                                                                      \
            __builtin_amdgcn_mfma_f32_16x16x32_bf16(a[m], BV1, acc[m][NLO + 1], 0, 0, 0);      \
    __builtin_amdgcn_s_setprio(0);                                                             \
  } while (0)

// P1(T): stage AH0(T+1); vm; BAR; read a8@s0(T); lgkm0; MFMA n01 (bA)
#define PHASE1(T, DOSTG, VMN)                                                                  \
  do {                                                                                         \
    if (DOSTG) STAGE_AH0((T) + 1);                                                             \
    VMN;                                                                                       \
    BAR();                                                                                     \
    const u16* bc_ = lds + ((T) & 1) * 32768;                                                  \
    _Pragma("unroll") for (int m = 0; m < 8; m++)                                              \
        a[m] = *(const short8*)(bc_ + aoff + m * 512);                                         \
    LGKM0();                                                                                   \
    MFMA16(0, bA[0], bA[1]);                                                                   \
  } while (0)

// P2(T): stage AH1(T+1); BAR; read bB4@s1(T); lgkm0; MFMA n23 (bA)
#define PHASE2(T, DOSTG)                                                                       \
  do {                                                                                         \
    if (DOSTG) STAGE_AH1((T) + 1);                                                             \
    BAR();                                                                                     \
    const u16* bc_ = lds + ((T) & 1) * 32768;                                                  \
    _Pragma("unroll") for (int n = 0; n < 4; n++)                                              \
        bB[n] = *(const short8*)(bc_ + boff + 4096 + n * 512);                                 \
    LGKM0();                                                                                   \
    MFMA16(2, bA[2], bA[3]);                                                                   \
  } while (0)

// P3(T): BAR; read a8@s1(T); lgkm0; MFMA n01 (bB)
#define PHASE3(T)                                                                              \
  do {                                                                                         \
    BAR();                                                                                     \
    const u16* bc_ = lds + ((T) & 1) * 32768;                                                  \
    _Pragma("unroll") for (int m = 0; m < 8; m++)                                              \
        a[m] = *(const short8*)(bc_ + aoff + 4096 + m * 512);                                  \
    LGKM0();                                                                                   \
    MFMA16(0, bB[0], bB[1]);                                                                   \
  } while (0)

// P4(T): stage BH0+BH1(T+2); vm; BAR; read bA4@s0(T+1); lgkm0; MFMA n23 (bB)
#define PHASE4(T, DOSTG, DORD, VMN)                                                            \
  do {                                                                                         \
    if (DOSTG) { STAGE_BH0((T) + 2); STAGE_BH1((T) + 2); }                                     \
    VMN;                                                                                       \
    BAR();                                                                                     \
    if (DORD) {                                                                                \
      const u16* bn_ = lds + (((T) + 1) & 1) * 32768;                                          \
      _Pragma("unroll") for (int n = 0; n < 4; n++)                                            \
          bA[n] = *(const short8*)(bn_ + boff + n * 512);                                      \
    }                                                                                          \
    LGKM0();                                                                                   \
    MFMA16(2, bB[2], bB[3]);                                                                   \
  } while (0)

  // prologue: B(0), A(0), B(1); vm(4) keeps B(1); BAR publishes; pre-read bA@s0(0)
  STAGE_BH0(0); STAGE_BH1(0); STAGE_AH0(0); STAGE_AH1(0); STAGE_BH0(1); STAGE_BH1(1);
  VMWAIT(4);
  BAR();
  {
    const u16* bc_ = lds;
#pragma unroll
    for (int n = 0; n < 4; n++) bA[n] = *(const short8*)(bc_ + boff + n * 512);
  }

  for (int T = 0; T < 14; ++T) {
    PHASE1(T, 1, VMWAIT(6));
    PHASE2(T, 1);
    PHASE3(T);
    PHASE4(T, 1, 1, VMWAIT(8));
  }
  // T=14: stages A(15) but not B(16); vm(4)@P4 retires B(15) (read this phase)
  PHASE1(14, 1, VMWAIT(6));
  PHASE2(14, 1);
  PHASE3(14);
  PHASE4(14, 0, 1, VMWAIT(4));
  // T=15: no stages; vm(0)@P1 drains A(15)
  PHASE1(15, 0, VMWAIT(0));
  PHASE2(15, 0);
  PHASE3(15);
  PHASE4(15, 0, 0, (void)0);

#undef PHASE1
#undef PHASE2
#undef PHASE3
#undef PHASE4
#undef MFMA16
#undef STAGE_AH0
#undef STAGE_AH1
#undef STAGE_BH0
#undef STAGE_BH1

  if (bn3 < 1024) {
    float scl = 0.18033688011112f;
    int rbase = bm + wr * 128 + quad * 4;
    int cbase = bn3 + wc * 64 + l15;
#pragma unroll
    for (int m = 0; m < 8; m++)
#pragma unroll
      for (int n = 0; n < 4; n++)
#pragma unroll
        for (int r = 0; r < 4; r++)
          qb[(size_t)(rbase + m * 16 + r) * 1024 + cbase + n * 16] = f2bf(acc[m][n][r] * scl);
  } else {
    int bnl = bn3 & 1023;
    int h = (bnl >> 6) + wc;
    int bh = (bm >> 11) * 16 + h;
    int ktb = ((bm & 2047) >> 6) + wr * 2;
    if (bn3 < 2048) {
      int lhi = ((l15 >> 3) & 1) * 32;
      int e = l15 & 7;
#pragma unroll
      for (int m = 0; m < 8; m++) {
        u16* kd = kpack + ((size_t)bh * 32 + ktb + (m >> 2)) * 4096;
        int krb = (m & 3) * 16 + quad * 4;
        int jm = (krb >> 5) * 4;
        int l31b = krb & 31;
#pragma unroll
        for (int n = 0; n < 4; n++)
#pragma unroll
          for (int r = 0; r < 4; r++) {
            int off = (jm + n) * 512 + (l31b + r + lhi) * 8 + e;
            kd[off] = f2bf(acc[m][n][r]);
          }
      }
    } else {
      int e0 = (quad & 1) * 4;
      int hi5 = (quad >> 1) * 32;
#pragma unroll
      for (int m = 0; m < 8; m++) {
        u16* vd = vpack + ((size_t)bh * 32 + ktb + (m >> 2)) * 4096;
#pragma unroll
        for (int n = 0; n < 4; n++) {
          int off = ((n >> 1) * 4 + (m & 3)) * 512 +
                    ((n & 1) * 16 + l15 + hi5) * 8 + e0;
          ushort4 wv;
          wv.x = f2bf(acc[m][n][0]);
          wv.y = f2bf(acc[m][n][1]);
          wv.z = f2bf(acc[m][n][2]);
          wv.w = f2bf(acc[m][n][3]);
          *(ushort4*)(vd + off) = wv;
        }
      }
    }
  }
}

// ==================== gemm_proj: 256x128, BK=64, SINGLE-BARRIER phases =============
// Same transform. Stages: P1 ALO(T+1), P2 AHI(T+1), P4 B(T+2). Waits: vm(4)@P1
// retires A(T); vm(6)@P4 retires B(T+1). Prologue B0,A0,B1 + vm(2); tail 4 -> 0.
__global__ __launch_bounds__(512, 2) void gemm_proj(const u16* __restrict__ A,
                                                    const u16* __restrict__ Bt,
                                                    float* __restrict__ Co) {
  __shared__ u16 lds[49152];  // 96 KB
  int tid = threadIdx.x;
  int w = tid >> 6, lane = tid & 63, l15 = lane & 15, quad = lane >> 4;
  int wr = w >> 1, wc = w & 1;

  int bid = blockIdx.x;
  int wgid = (bid & 7) * 32 + (bid >> 3);
  int bm = (wgid >> 3) * 256;
  int bn = (wgid & 7) * 128;

  int srow = lane >> 2;
  int kswz = ((lane & 3) * 8) ^ ((lane >> 5) << 4);
  const u16* gA0 = A + (size_t)(bm + w * 16 + srow) * 1024 + kswz;
  const u16* gA1 = A + (size_t)(bm + 128 + w * 16 + srow) * 1024 + kswz;
  const u16* gB0 = Bt + (size_t)(bn + w * 16 + srow) * 1024 + kswz;

  int kq = (quad * 8) ^ ((l15 & 8) << 1);
  int aoff = (wr >> 1) * 8192 + (wr & 1) * 2048 + l15 * 32 + kq;
  int boff = 16384 + wc * 2048 + l15 * 32 + kq;

  f32x4 acc[4][4];
#pragma unroll
  for (int m = 0; m < 4; m++)
#pragma unroll
    for (int n = 0; n < 4; n++) acc[m][n] = (f32x4)0.0f;

  short8 a[4], bA[4], bB[4];

#define PSTG_ALO(T)                                           \
  do {                                                        \
    u16* d_ = lds + ((T) & 1) * 24576 + w * 512;              \
    gll16(gA0 + (size_t)(T) * 64, d_);                        \
    gll16(gA0 + (size_t)(T) * 64 + 32, d_ + 4096);            \
  } while (0)
#define PSTG_AHI(T)                                           \
  do {                                                        \
    u16* d_ = lds + ((T) & 1) * 24576 + 8192 + w * 512;       \
    gll16(gA1 + (size_t)(T) * 64, d_);                        \
    gll16(gA1 + (size_t)(T) * 64 + 32, d_ + 4096);            \
  } while (0)
#define PSTG_B(T)                                             \
  do {                                                        \
    u16* d_ = lds + ((T) & 1) * 24576 + 16384 + w * 512;      \
    gll16(gB0 + (size_t)(T) * 64, d_);                        \
    gll16(gB0 + (size_t)(T) * 64 + 32, d_ + 4096);            \
  } while (0)

#define MFMA8(NLO, BV0, BV1)                                                                   \
  do {                                                                                         \
    __builtin_amdgcn_s_setprio(1);                                                             \
    _Pragma("unroll") for (int m = 0; m < 4; m++)                                              \
        acc[m][NLO] = __builtin_amdgcn_mfma_f32_16x16x32_bf16(a[m], BV0, acc[m][NLO], 0, 0, 0);\
    _Pragma("unroll") for (int m = 0; m < 4; m++)                                              \
        acc[m][NLO + 1] =                                                                      \
            __builtin_amdgcn_mfma_f32_16x16x32_bf16(a[m], BV1, acc[m][NLO + 1], 0, 0, 0);      \
    __builtin_amdgcn_s_setprio(0);                                                             \
  } while (0)

#define PPH1(T, DOSTG, VMN)                                                                    \
  do {                                                                                         \
    if (DOSTG) PSTG_ALO((T) + 1);                                                              \
    VMN;                                                                                       \
    BAR();                                                                                     \
    const u16* bc_ = lds + ((T) & 1) * 24576;                                                  \
    _Pragma("unroll") for (int m = 0; m < 4; m++)                                              \
        a[m] = *(const short8*)(bc_ + aoff + m * 512);                                         \
    LGKM0();                                                                                   \
    MFMA8(0, bA[0], bA[1]);                                                                    \
  } while (0)

#define PPH2(T, DOSTG)                                                                         \
  do {                                                                                         \
    if (DOSTG) PSTG_AHI((T) + 1);                                                              \
    BAR();                                                                                     \
    const u16* bc_ = lds + ((T) & 1) * 24576;                                                  \
    _Pragma("unroll") for (int n = 0; n < 4; n++)                                              \
        bB[n] = *(const short8*)(bc_ + boff + 4096 + n * 512);                                 \
    LGKM0();                                                                                   \
    MFMA8(2, bA[2], bA[3]);                                                                    \
  } while (0)

#define PPH3(T)                                                                                \
  do {                                                                                         \
    BAR();                                                                                     \
    const u16* bc_ = lds + ((T) & 1) * 24576;                                                  \
    _Pragma("unroll") for (int m = 0; m < 4; m++)                                              \
        a[m] = *(const short8*)(bc_ + aoff + 4096 + m * 512);                                  \
    LGKM0();                                                                                   \
    MFMA8(0, bB[0], bB[1]);                                                                    \
  } while (0)

#define PPH4(T, DOSTG, DORD, VMN)                                                              \
  do {                                                                                         \
    if (DOSTG) PSTG_B((T) + 2);                                                                \
    VMN;                                                                                       \
    BAR();                                                                                     \
    if (DORD) {                                                                                \
      const u16* bn_ = lds + (((T) + 1) & 1) * 24576;                                          \
      _Pragma("unroll") for (int n = 0; n < 4; n++)                                            \
          bA[n] = *(const short8*)(bn_ + boff + n * 512);                                      \
    }                                                                                          \
    LGKM0();                                                                                   \
    MFMA8(2, bB[2], bB[3]);                                                                    \
  } while (0)

  // prologue: B(0), A(0), B(1); vm(2) keeps B(1); BAR; pre-read bA@s0(0)
  PSTG_B(0); PSTG_ALO(0); PSTG_AHI(0); PSTG_B(1);
  VMWAIT(2);
  BAR();
  {
    const u16* bc_ = lds;
#pragma unroll
    for (int n = 0; n < 4; n++) bA[n] = *(const short8*)(bc_ + boff + n * 512);
  }

  for (int T = 0; T < 14; ++T) {
    PPH1(T, 1, VMWAIT(4));
    PPH2(T, 1);
    PPH3(T);
    PPH4(T, 1, 1, VMWAIT(6));
  }
  PPH1(14, 1, VMWAIT(4));
  PPH2(14, 1);
  PPH3(14);
  PPH4(14, 0, 1, VMWAIT(4));   // retires B(15), keeps A(15)
  PPH1(15, 0, VMWAIT(0));      // drains A(15)
  PPH2(15, 0);
  PPH3(15);
  PPH4(15, 0, 0, (void)0);

#undef PPH1
#undef PPH2
#undef PPH3
#undef PPH4
#undef MFMA8
#undef PSTG_ALO
#undef PSTG_AHI
#undef PSTG_B

  int rbase = bm + wr * 64 + quad * 4;
  int cbase = bn + wc * 64 + l15;
#pragma unroll
  for (int m = 0; m < 4; m++)
#pragma unroll
    for (int n = 0; n < 4; n++)
#pragma unroll
      for (int r = 0; r < 4; r++)
        Co[(size_t)(rbase + m * 16 + r) * 1024 + cbase + n * 16] = acc[m][n][r];
}

// ---------------- flash attention (round-7 verified, unchanged) ----------------
__global__ __launch_bounds__(256, 2) void attn_kernel(const u16* __restrict__ qbuf,
                                                      const u16* __restrict__ kpack,
                                                      const u16* __restrict__ vpack,
                                                      u16* __restrict__ ctx) {
  int t = threadIdx.x;
  int wave = t >> 6, lane = t & 63, l31 = lane & 31, hi = lane >> 5;
  int bh = blockIdx.x;
  int s = (int)blockIdx.y * 4 + wave;
  int b = bh >> 4, h = bh & 15;
  int rowbase = b * 2048;
  int hi4 = hi * 4;

  const u16* kp = kpack + (size_t)bh * (32 * 4096) + lane * 8;
  const u16* vp = vpack + (size_t)bh * (32 * 4096) + lane * 8;

#pragma unroll
  for (int ph = 0; ph < 2; ph++) {
    int strip = ph ? 63 - s : s;
    int q0 = strip * 32;
    int q_lane = q0 + l31;

    const u16* qp = qbuf + (size_t)(rowbase + q_lane) * 1024 + h * 64 + hi * 8;
    short8 qf[4];
#pragma unroll
    for (int ks = 0; ks < 4; ks++) qf[ks] = *(const short8*)(qp + ks * 16);

    float l_run = 0.0f;
    f32x16 o[2];
    o[0] = (f32x16)0.0f; o[1] = (f32x16)0.0f;
    int ktmax = (q0 + 31) >> 6;

    for (int kt = 0; kt <= ktmax; kt++) {
      const u16* kb = kp + kt * 4096;
      const u16* vb = vp + kt * 4096;

      short8 ka[8], vv[8];
#pragma unroll
      for (int j = 0; j < 8; j++) {
        ka[j] = *(const short8*)(kb + j * 512);
        vv[j] = *(const short8*)(vb + j * 512);
      }

      f32x16 st0 = (f32x16)0.0f, st1 = (f32x16)0.0f;
#pragma unroll
      for (int ks = 0; ks < 4; ks++) {
        st0 = __builtin_amdgcn_mfma_f32_32x32x16_bf16(ka[ks], qf[ks], st0, 0, 0, 0);
        st1 = __builtin_amdgcn_mfma_f32_32x32x16_bf16(ka[4 + ks], qf[ks], st1, 0, 0, 0);
      }

      unsigned pk[2][8];
      if (kt == ktmax) {
#pragma unroll
        for (int ii = 0; ii < 8; ii++) {
          int key = kt * 64 + ((2 * ii) & 3) + 8 * ((2 * ii) >> 2) + hi4;
          float p00 = (key     <= q_lane) ? __builtin_amdgcn_exp2f(st0[2 * ii])     : 0.0f;
          float p01 = (key + 1 <= q_lane) ? __builtin_amdgcn_exp2f(st0[2 * ii + 1]) : 0.0f;
          float p10 = (key + 32 <= q_lane) ? __builtin_amdgcn_exp2f(st1[2 * ii])     : 0.0f;
          float p11 = (key + 33 <= q_lane) ? __builtin_amdgcn_exp2f(st1[2 * ii + 1]) : 0.0f;
          l_run += p00 + p01 + p10 + p11;
          pk[0][ii] = ((__float_as_uint(p00) + 0x8000u) >> 16) |
                      ((__float_as_uint(p01) + 0x8000u) & 0xffff0000u);
          pk[1][ii] = ((__float_as_uint(p10) + 0x8000u) >> 16) |
                      ((__float_as_uint(p11) + 0x8000u) & 0xffff0000u);
        }
      } else {
#pragma unroll
        for (int ii = 0; ii < 8; ii++) {
          float p00 = __builtin_amdgcn_exp2f(st0[2 * ii]);
          float p01 = __builtin_amdgcn_exp2f(st0[2 * ii + 1]);
          float p10 = __builtin_amdgcn_exp2f(st1[2 * ii]);
          float p11 = __builtin_amdgcn_exp2f(st1[2 * ii + 1]);
          l_run += p00 + p01 + p10 + p11;
          pk[0][ii] = ((__float_as_uint(p00) + 0x8000u) >> 16) |
                      ((__float_as_uint(p01) + 0x8000u) & 0xffff0000u);
          pk[1][ii] = ((__float_as_uint(p10) + 0x8000u) >> 16) |
                      ((__float_as_uint(p11) + 0x8000u) & 0xffff0000u);
        }
      }

      short8 pf[4];
#pragma unroll
      for (int ks2 = 0; ks2 < 4; ks2++) {
        int km = ks2 >> 1, h4 = (ks2 & 1) * 4;
        unsigned A0 = pk[km][h4 + 0], A1 = pk[km][h4 + 1];
        unsigned B0 = pk[km][h4 + 2], B1 = pk[km][h4 + 3];
        unsigned tA0 = (unsigned)__shfl_xor((int)A0, 32);
        unsigned tA1 = (unsigned)__shfl_xor((int)A1, 32);
        unsigned tB0 = (unsigned)__shfl_xor((int)B0, 32);
        unsigned tB1 = (unsigned)__shfl_xor((int)B1, 32);
        union { unsigned u[4]; short8 sh; } fr;
        fr.u[0] = hi ? tB0 : A0;
        fr.u[1] = hi ? tB1 : A1;
        fr.u[2] = hi ? B0 : tA0;
        fr.u[3] = hi ? B1 : tA1;
        pf[ks2] = fr.sh;
      }

#pragma unroll
      for (int am = 0; am < 2; am++)
#pragma unroll
        for (int ks2 = 0; ks2 < 4; ks2++)
          o[am] = __builtin_amdgcn_mfma_f32_32x32x16_bf16(vv[am * 4 + ks2], pf[ks2], o[am], 0, 0, 0);
    }

    float l_tot = l_run + __shfl_xor(l_run, 32);
    float inv = 1.0f / l_tot;
    size_t obase = (size_t)(rowbase + q_lane) * 1024 + h * 64;
#pragma unroll
    for (int am = 0; am < 2; am++)
#pragma unroll
      for (int k = 0; k < 4; k++) {
        ushort4 w;
        w.x = f2bf(o[am][4 * k + 0] * inv);
        w.y = f2bf(o[am][4 * k + 1] * inv);
        w.z = f2bf(o[am][4 * k + 2] * inv);
        w.w = f2bf(o[am][4 * k + 3] * inv);
        *(ushort4*)&ctx[obase + am * 32 + k * 8 + hi4] = w;
      }
  }
}

// ---------------- launch ----------------
extern "C" void kernel_launch(void* const* d_in, const int* in_sizes, int n_in,
                              void* d_out, int out_size, void* d_ws, size_t ws_size,
                              hipStream_t stream) {
  const float* x      = (const float*)d_in[0];
  const float* w_qkv  = (const float*)d_in[1];
  const float* w_proj = (const float*)d_in[2];
  float* out = (float*)d_out;

  char* ws = (char*)d_ws;
  const size_t MB = 1024 * 1024;
  u16* qbuf   = (u16*)(ws);
  u16* kpack  = (u16*)(ws + 16 * MB);
  u16* vpack  = (u16*)(ws + 32 * MB);
  u16* xb     = (u16*)(ws + 48 * MB);
  u16* ctx    = (u16*)(ws + 64 * MB);
  u16* wqkvT  = (u16*)(ws + 80 * MB);
  u16* wprojT = (u16*)(ws + 86 * MB);

  prep_kernel<<<12288, 256, 0, stream>>>(x, xb, w_qkv, wqkvT, w_proj, wprojT);
  gemm_qkv<<<dim3(384), 512, 0, stream>>>(xb, wqkvT, qbuf, kpack, vpack);
  attn_kernel<<<dim3(64, 8), 256, 0, stream>>>(qbuf, kpack, vpack, ctx);
  gemm_proj<<<dim3(256), 512, 0, stream>>>(ctx, wprojT, out);
}